// Round 16
// baseline (753.310 us; speedup 1.0000x reference)
//
#include <hip/hip_runtime.h>
#include <hip/hip_bf16.h>

#define BB 16
#define NN 8192
#define GG 512
#define KK 32
#define DD 128

typedef __attribute__((ext_vector_type(8))) short bf16x8;
typedef __attribute__((ext_vector_type(4))) float f32x4;
typedef __attribute__((ext_vector_type(2))) float f32x2;
typedef __attribute__((ext_vector_type(2))) unsigned int u32x2;
typedef __attribute__((ext_vector_type(4))) unsigned int u32x4;
typedef __attribute__((ext_vector_type(2))) unsigned long long u64x2;

__device__ __forceinline__ unsigned short f2bf(float f){
  unsigned int u = __builtin_bit_cast(unsigned int, f);
  unsigned int r = (u + 0x7FFFu + ((u >> 16) & 1u)) >> 16;
  return (unsigned short)r;
}
__device__ __forceinline__ float bf2f(unsigned short h){
  unsigned int u = ((unsigned int)h) << 16;
  return __builtin_bit_cast(float, u);
}

// DPP wave64 reductions: row_shr 1/2/4/8 then row_bcast15/31; result in lane 63.
__device__ __forceinline__ float wave_max_f32(float v){
  int x = __builtin_bit_cast(int, v);
#define STEPMAX(C) { int y = __builtin_amdgcn_update_dpp(x, x, C, 0xF, 0xF, false); \
  float f = fmaxf(__builtin_bit_cast(float,x), __builtin_bit_cast(float,y)); x = __builtin_bit_cast(int,f); }
  STEPMAX(0x111) STEPMAX(0x112) STEPMAX(0x114) STEPMAX(0x118) STEPMAX(0x142) STEPMAX(0x143)
#undef STEPMAX
  return __builtin_bit_cast(float, __builtin_amdgcn_readlane(x, 63));
}
__device__ __forceinline__ float wave_min_f32(float v){
  int x = __builtin_bit_cast(int, v);
#define STEPMIN(C) { int y = __builtin_amdgcn_update_dpp(x, x, C, 0xF, 0xF, false); \
  float f = fminf(__builtin_bit_cast(float,x), __builtin_bit_cast(float,y)); x = __builtin_bit_cast(int,f); }
  STEPMIN(0x111) STEPMIN(0x112) STEPMIN(0x114) STEPMIN(0x118) STEPMIN(0x142) STEPMIN(0x143)
#undef STEPMIN
  return __builtin_bit_cast(float, __builtin_amdgcn_readlane(x, 63));
}
__device__ __forceinline__ int wave_min_i32(int v){
  int x = v;
#define STEPMNI(C) { int y = __builtin_amdgcn_update_dpp(x, x, C, 0xF, 0xF, false); \
  x = (y < x) ? y : x; }
  STEPMNI(0x111) STEPMNI(0x112) STEPMNI(0x114) STEPMNI(0x118) STEPMNI(0x142) STEPMNI(0x143)
#undef STEPMNI
  return __builtin_amdgcn_readlane(x, 63);
}

// ---------------- KNN 2-wave group worker (frozen R13; used in fps phases) --
__device__ __forceinline__ void knn_group(int bg, int t128,
    const float* __restrict__ xs, const float* __restrict__ ys,
    const float* __restrict__ zs, const float* __restrict__ pps,
    const float* __restrict__ center, int* __restrict__ kidx,
    unsigned long long (*wlist)[KK], int* outidx)
{
#pragma clang fp contract(off)
  int lane = t128 & 63, w = t128 >> 6;
  int b = bg >> 9;
  const float cx = center[(size_t)bg*3+0];
  const float cy = center[(size_t)bg*3+1];
  const float cz = center[(size_t)bg*3+2];
  const float ccv = (cx*cx + cy*cy) + cz*cz;   // same expr tree as ref cc
  const float* xb = xs  + (size_t)b*NN;
  const float* yb = ys  + (size_t)b*NN;
  const float* zb = zs  + (size_t)b*NN;
  const float* pb = pps + (size_t)b*NN;

  f32x2 d2v[32];
  float gmin[8]; int gidx[8];
#pragma unroll
  for (int gi = 0; gi < 8; ++gi){ gmin[gi] = 3.4e38f; gidx[gi] = 0x7FFFFFFF; }
  int nb = w*128 + 2*lane;
  f32x2 cxv = (f32x2){cx, cx}, cyv = (f32x2){cy, cy}, czv = (f32x2){cz, cz};
  f32x2 ccvv = (f32x2){ccv, ccv};
#pragma unroll
  for (int q = 0; q < 32; ++q){
    int n0 = q*256 + nb;
    f32x2 x = *(const f32x2*)(xb + n0);
    f32x2 y = *(const f32x2*)(yb + n0);
    f32x2 z = *(const f32x2*)(zb + n0);
    f32x2 pp = *(const f32x2*)(pb + n0);
    f32x2 dot = (cxv*x + cyv*y) + czv*z;
    f32x2 d = (ccvv + pp) - 2.0f*dot;
    d2v[q] = d;
    int gi = q >> 2;
    if (d.x < gmin[gi]){ gmin[gi] = d.x; gidx[gi] = n0; }
    if (d.y < gmin[gi]){ gmin[gi] = d.y; gidx[gi] = n0 + 1; }
  }
  float bv = gmin[0]; int bi = gidx[0];
#pragma unroll
  for (int gi = 1; gi < 8; ++gi)
    if (gmin[gi] < bv){ bv = gmin[gi]; bi = gidx[gi]; }

  unsigned long long mykey = ~0ULL;
  for (int k = 0; k < KK; ++k){
    float wmin = wave_min_f32(bv);
    unsigned long long mask = __ballot(bv == wmin);
    int n_win;
    if (__popcll(mask) == 1){
      n_win = __builtin_amdgcn_readlane(bi, (int)__builtin_ctzll(mask));
    } else {
      int cand = (bv == wmin) ? bi : 0x7FFFFFFF;
      n_win = wave_min_i32(cand);
    }
    if (lane == k){
      unsigned int fm = __builtin_bit_cast(unsigned int, wmin);
      unsigned int mapd = fm ^ (unsigned int)(((int)fm >> 31) | 0x80000000);
      mykey = ((unsigned long long)mapd << 32) | (unsigned int)n_win;
    }
    if (bi == n_win){                     // owner lane only
#define RESCAN2(GI) { \
      float nm = 3.4e38f; int ni = 0x7FFFFFFF; \
      _Pragma("unroll") \
      for (int j = 0; j < 4; ++j){ \
        int q = GI*4 + j; \
        int n0 = q*256 + nb; \
        f32x2 v = d2v[q]; \
        if (n0 == n_win) v.x = 3.4e38f; \
        if (n0 + 1 == n_win) v.y = 3.4e38f; \
        d2v[q] = v; \
        if (v.x < nm){ nm = v.x; ni = n0; } \
        if (v.y < nm){ nm = v.y; ni = n0 + 1; } } \
      gmin[GI] = nm; gidx[GI] = ni; }
      switch (n_win >> 10){
        case 0: RESCAN2(0); break;
        case 1: RESCAN2(1); break;
        case 2: RESCAN2(2); break;
        case 3: RESCAN2(3); break;
        case 4: RESCAN2(4); break;
        case 5: RESCAN2(5); break;
        case 6: RESCAN2(6); break;
        default: RESCAN2(7); break;
      }
#undef RESCAN2
      bv = gmin[0]; bi = gidx[0];
#pragma unroll
      for (int gi = 1; gi < 8; ++gi)
        if (gmin[gi] < bv){ bv = gmin[gi]; bi = gidx[gi]; }
    }
  }

  if (lane < KK) wlist[w][lane] = mykey;
  __syncthreads();
  if (lane < KK){
    unsigned long long K = mykey;
    const unsigned long long* other = wlist[1 - w];
    int cnt = 0;
#pragma unroll
    for (int j = 0; j < KK; ++j) cnt += (other[j] < K) ? 1 : 0;
    int rank = lane + cnt;
    if (rank < KK) outidx[rank] = (int)(unsigned int)K;
  }
  __syncthreads();
  if (t128 < KK) kidx[(size_t)bg*KK + t128] = outidx[t128];
}

// ---------------- KNN 1-wave group worker (tail; no LDS, no barriers) -------
// 128 pts/lane: n = q*128 + 2*lane + {0,1}, q in [0,64). ~175 VGPR -> needs
// launch_bounds <= 256 (VGPR cap 512). Identical key order => bit-exact.
__device__ __forceinline__ void knn_group1(int bg, int lane,
    const float* __restrict__ xs, const float* __restrict__ ys,
    const float* __restrict__ zs, const float* __restrict__ pps,
    const float* __restrict__ center, int* __restrict__ kidx)
{
#pragma clang fp contract(off)
  int b = bg >> 9;
  const float cx = center[(size_t)bg*3+0];
  const float cy = center[(size_t)bg*3+1];
  const float cz = center[(size_t)bg*3+2];
  const float ccv = (cx*cx + cy*cy) + cz*cz;   // same expr tree as ref cc
  const float* xb = xs  + (size_t)b*NN;
  const float* yb = ys  + (size_t)b*NN;
  const float* zb = zs  + (size_t)b*NN;
  const float* pb = pps + (size_t)b*NN;

  f32x2 d2v[64];
  float gmin[8]; int gidx[8];
#pragma unroll
  for (int gi = 0; gi < 8; ++gi){ gmin[gi] = 3.4e38f; gidx[gi] = 0x7FFFFFFF; }
  int nb = 2*lane;
  f32x2 cxv = (f32x2){cx, cx}, cyv = (f32x2){cy, cy}, czv = (f32x2){cz, cz};
  f32x2 ccvv = (f32x2){ccv, ccv};
#pragma unroll
  for (int q = 0; q < 64; ++q){
    int n0 = q*128 + nb;
    f32x2 x = *(const f32x2*)(xb + n0);
    f32x2 y = *(const f32x2*)(yb + n0);
    f32x2 z = *(const f32x2*)(zb + n0);
    f32x2 pp = *(const f32x2*)(pb + n0);
    f32x2 dot = (cxv*x + cyv*y) + czv*z;
    f32x2 d = (ccvv + pp) - 2.0f*dot;
    d2v[q] = d;
    int gi = q >> 3;
    if (d.x < gmin[gi]){ gmin[gi] = d.x; gidx[gi] = n0; }
    if (d.y < gmin[gi]){ gmin[gi] = d.y; gidx[gi] = n0 + 1; }
  }
  float bv = gmin[0]; int bi = gidx[0];
#pragma unroll
  for (int gi = 1; gi < 8; ++gi)
    if (gmin[gi] < bv){ bv = gmin[gi]; bi = gidx[gi]; }

  int kq = 0;
  for (int k = 0; k < KK; ++k){
    float wmin = wave_min_f32(bv);
    unsigned long long mask = __ballot(bv == wmin);
    int n_win;
    if (__popcll(mask) == 1){
      n_win = __builtin_amdgcn_readlane(bi, (int)__builtin_ctzll(mask));
    } else {
      int cand = (bv == wmin) ? bi : 0x7FFFFFFF;
      n_win = wave_min_i32(cand);
    }
    if (lane == k) kq = n_win;
    if (bi == n_win){                     // owner lane only
#define RESCAN1(GI) { \
      float nm = 3.4e38f; int ni = 0x7FFFFFFF; \
      _Pragma("unroll") \
      for (int j = 0; j < 8; ++j){ \
        int q = GI*8 + j; \
        int n0 = q*128 + nb; \
        f32x2 v = d2v[q]; \
        if (n0 == n_win) v.x = 3.4e38f; \
        if (n0 + 1 == n_win) v.y = 3.4e38f; \
        d2v[q] = v; \
        if (v.x < nm){ nm = v.x; ni = n0; } \
        if (v.y < nm){ nm = v.y; ni = n0 + 1; } } \
      gmin[GI] = nm; gidx[GI] = ni; }
      switch (n_win >> 10){
        case 0: RESCAN1(0); break;
        case 1: RESCAN1(1); break;
        case 2: RESCAN1(2); break;
        case 3: RESCAN1(3); break;
        case 4: RESCAN1(4); break;
        case 5: RESCAN1(5); break;
        case 6: RESCAN1(6); break;
        default: RESCAN1(7); break;
      }
#undef RESCAN1
      bv = gmin[0]; bi = gidx[0];
#pragma unroll
      for (int gi = 1; gi < 8; ++gi)
        if (gmin[gi] < bv){ bv = gmin[gi]; bi = gidx[gi]; }
    }
  }
  if (lane < KK) kidx[(size_t)bg*KK + lane] = kq;
}

// ---------------- FPS quarter (frozen R15) ----------------------------------
__device__ __forceinline__ void fps_part(const float* __restrict__ xyz,
    float* __restrict__ center_out, float* __restrict__ ddws,
    int b, int t, int g0, int g1, bool save_dd, char* lds)
{
#pragma clang fp contract(off)
  float (*tbl)[4]    = (float(*)[4])lds;                       // 128 KB
  float (*outbuf)[4] = (float(*)[4])(lds + 131072);            // 2 KB
  unsigned long long (*slot)[2] =
      (unsigned long long(*)[2])(lds + 131072 + 2048);         // 48 B
  int lane = t & 63, wid = t >> 6;
  const float* base = xyz + (size_t)b * NN * 3;
  f32x2 px[4], py[4], pz[4], dd[4];
  if (g0 == 1){
#pragma unroll
    for (int i = 0; i < 4; ++i) dd[i] = (f32x2){1e10f, 1e10f};
  } else {
    const float* dp = ddws + ((size_t)b*1024 + t)*8;
    f32x4 s0 = *(const f32x4*)dp;
    f32x4 s1 = *(const f32x4*)(dp + 4);
    dd[0] = (f32x2){s0[0], s0[1]};
    dd[1] = (f32x2){s0[2], s0[3]};
    dd[2] = (f32x2){s1[0], s1[1]};
    dd[3] = (f32x2){s1[2], s1[3]};
  }
#pragma unroll
  for (int i = 0; i < 4; ++i){
    int n0 = i*2048 + t, n1 = n0 + 1024;
    float x0 = base[n0*3+0], y0 = base[n0*3+1], z0 = base[n0*3+2];
    float x1 = base[n1*3+0], y1 = base[n1*3+1], z1 = base[n1*3+2];
    px[i] = (f32x2){x0, x1}; py[i] = (f32x2){y0, y1}; pz[i] = (f32x2){z0, z1};
    f32x4 c0 = {x0, y0, z0, 0.f}, c1 = {x1, y1, z1, 0.f};
    *(f32x4*)&tbl[n0][0] = c0;
    *(f32x4*)&tbl[n1][0] = c1;
  }
  float lx, ly, lz;
  if (g0 == 1){ lx = base[0]; ly = base[1]; lz = base[2]; }
  else {
    lx = center_out[((size_t)b*GG + g0 - 1)*3 + 0];
    ly = center_out[((size_t)b*GG + g0 - 1)*3 + 1];
    lz = center_out[((size_t)b*GG + g0 - 1)*3 + 2];
  }
  if (t < 6) slot[t >> 1][t & 1] = 0;
  __syncthreads();
  for (int g = g0; g < g1; ++g){
    f32x2 lxv = (f32x2){lx, lx}, lyv = (f32x2){ly, ly}, lzv = (f32x2){lz, lz};
    f32x2 vm = (f32x2){-1.f, -1.f};
#pragma unroll
    for (int i = 0; i < 4; ++i){
      f32x2 dx = px[i] - lxv, dy = py[i] - lyv, dz = pz[i] - lzv;
      f32x2 s = (dx*dx + dy*dy) + dz*dz;
      f32x2 nd = __builtin_elementwise_min(dd[i], s);
      dd[i] = nd;
      vm = __builtin_elementwise_max(vm, nd);
    }
    float m = fmaxf(vm.x, vm.y);
    int mi = 0x7FFFFFFF;
#pragma unroll
    for (int i = 3; i >= 0; --i){
      int n0 = i*2048 + t;
      if (dd[i].y == m) mi = n0 + 1024;
      if (dd[i].x == m) mi = n0;
    }
    float wmax = wave_max_f32(m);
    bool cnd = (m == wmax);
    unsigned long long mask = __ballot(cnd);
    int n_wave;
    if (__popcll(mask) == 1){
      n_wave = __builtin_amdgcn_readlane(mi, (int)__builtin_ctzll(mask));
    } else {
      int cand = cnd ? mi : 0x7FFFFFFF;
      n_wave = wave_min_i32(cand);
    }
    unsigned long long key =
        ((unsigned long long)__builtin_bit_cast(unsigned int, wmax) << 32)
      | (unsigned int)(~n_wave);
    int p = g - (g/3)*3;                             // g % 3
    if (lane == 0) atomicMax(&slot[p][wid & 1], key);
    __syncthreads();
    u64x2 sA = *(const u64x2*)&slot[p][0];
    unsigned long long M = sA.x > sA.y ? sA.x : sA.y;
    int n_win = (int)~((unsigned int)M);
    f32x4 cw = *(const f32x4*)&tbl[n_win][0];
    lx = cw[0]; ly = cw[1]; lz = cw[2];
    if (t == 0) *(f32x4*)&outbuf[g - g0][0] = cw;
    if (t < 2){
      int z = p + 2; if (z >= 3) z -= 3;             // (g+2) % 3
      slot[z][t] = 0;
    }
  }
  __syncthreads();
  if (t < g1 - g0){
    int g = g0 + t;
    center_out[((size_t)b*GG + g)*3 + 0] = outbuf[t][0];
    center_out[((size_t)b*GG + g)*3 + 1] = outbuf[t][1];
    center_out[((size_t)b*GG + g)*3 + 2] = outbuf[t][2];
  }
  if (g0 == 1 && t == 0){
    center_out[((size_t)b*GG)*3 + 0] = base[0];
    center_out[((size_t)b*GG)*3 + 1] = base[1];
    center_out[((size_t)b*GG)*3 + 2] = base[2];
  }
  if (save_dd){
    f32x4 s0 = {dd[0].x, dd[0].y, dd[1].x, dd[1].y};
    f32x4 s1 = {dd[2].x, dd[2].y, dd[3].x, dd[3].y};
    float* dp = ddws + ((size_t)b*1024 + t)*8;
    *(f32x4*)dp       = s0;
    *(f32x4*)(dp + 4) = s1;
  }
}

// ---------------- GEMM body (frozen R14) ------------------------------------
template<int OC, int MODE, bool STATS, bool STORE, bool POOL>
__device__ __forceinline__ void gemm_body(int sbid, int t,
    const unsigned short* __restrict__ Wbf, const float* __restrict__ bias,
    const unsigned short* __restrict__ pointsbf, const int* __restrict__ kidx,
    const unsigned short* __restrict__ Xin,
    const float* __restrict__ psum_in, const float* __restrict__ gin,
    const float* __restrict__ bein,
    unsigned short* __restrict__ Yout, float* __restrict__ psum,
    float* __restrict__ rawmax, float* __restrict__ rawmin,
    unsigned short* smem, float* ssc, float* ssh)
{
  constexpr int MF = OC / 64;
  int l = t & 63, w = t >> 6;
  int l15 = l & 15, lh = l >> 4;
  int jbase = sbid * 64;
  int obase = w * (OC / 4);
  int slot = sbid & 63;

  if constexpr (MODE == 1){
    if (t < 128){
      float s = 0.f, q = 0.f;
#pragma unroll
      for (int sl = 0; sl < 64; ++sl){
        s += psum_in[sl*128 + t];
        q += psum_in[64*128 + sl*128 + t];
      }
      const float inv = 1.f / 262144.f;    // B*K*G
      float mean = s * inv;
      float var  = q * inv - mean*mean;
      float sc = gin[t] * rsqrtf(var + 1e-5f);
      ssc[t] = sc;
      ssh[t] = bein[t] - mean*sc;
    }
  }

  bf16x8 a[MF][4];
#pragma unroll
  for (int m = 0; m < MF; ++m)
#pragma unroll
    for (int kf = 0; kf < 4; ++kf){
      int row = obase + m*16 + l15;
      int c8  = kf*32 + lh*8;
      a[m][kf] = *(const bf16x8*)(Wbf + (size_t)row*128 + c8);
    }

  if constexpr (MODE == 1) __syncthreads();

#pragma unroll
  for (int q = 0; q < 4; ++q){
    int ci = q*256 + t;
    int j = ci >> 4, cc = ci & 15;
    unsigned short* dst = &smem[j*128 + ((cc ^ (j & 15)) * 8)];
    if constexpr (MODE == 0){
      int jg = jbase + j;
      int bb = jg >> 14;
      int row = kidx[jg];
      const unsigned short* src = pointsbf + ((size_t)bb*NN + row)*DD + cc*8;
      *(u32x4*)dst = *(const u32x4*)src;
    } else {
      const unsigned short* src = Xin + ((size_t)(jbase + j))*128 + cc*8;
      u32x4 v = *(const u32x4*)src;
      int c0 = cc * 8;
      unsigned int wo[4];
#pragma unroll
      for (int p = 0; p < 4; ++p){
        float x0 = bf2f((unsigned short)(v[p] & 0xFFFFu));
        float x1 = bf2f((unsigned short)(v[p] >> 16));
        x0 = fmaxf(fmaf(x0, ssc[c0 + 2*p],     ssh[c0 + 2*p]),     0.f);
        x1 = fmaxf(fmaf(x1, ssc[c0 + 2*p + 1], ssh[c0 + 2*p + 1]), 0.f);
        wo[p] = f2bf(x0) | ((unsigned int)f2bf(x1) << 16);
      }
      u32x4 pv = {wo[0], wo[1], wo[2], wo[3]};
      *(u32x4*)dst = pv;
    }
  }
  __syncthreads();

  f32x4 acc[MF][4];
#pragma unroll
  for (int m = 0; m < MF; ++m)
#pragma unroll
    for (int n = 0; n < 4; ++n)
      acc[m][n] = (f32x4){0.f, 0.f, 0.f, 0.f};

#pragma unroll
  for (int n = 0; n < 4; ++n){
    bf16x8 bfr[4];
    int j = n*16 + l15;
#pragma unroll
    for (int kf = 0; kf < 4; ++kf){
      int ch = kf*4 + lh;
      bfr[kf] = *(const bf16x8*)&smem[j*128 + ((ch ^ (j & 15)) * 8)];
    }
#pragma unroll
    for (int m = 0; m < MF; ++m)
#pragma unroll
      for (int kf = 0; kf < 4; ++kf)
        acc[m][n] = __builtin_amdgcn_mfma_f32_16x16x32_bf16(a[m][kf], bfr[kf], acc[m][n], 0, 0, 0);
  }

#pragma unroll
  for (int m = 0; m < MF; ++m){
    int o0 = obase + m*16 + lh*4;
    f32x4 bv = *(const f32x4*)(bias + o0);
#pragma unroll
    for (int n = 0; n < 4; ++n) acc[m][n] += bv;
  }

  if constexpr (STATS){
#pragma unroll
    for (int m = 0; m < MF; ++m){
#pragma unroll
      for (int r = 0; r < 4; ++r){
        float s = 0.f, q2 = 0.f;
#pragma unroll
        for (int n = 0; n < 4; ++n){ float v = acc[m][n][r]; s += v; q2 += v*v; }
        s  += __shfl_xor(s, 1);  s  += __shfl_xor(s, 2);  s  += __shfl_xor(s, 4);  s  += __shfl_xor(s, 8);
        q2 += __shfl_xor(q2, 1); q2 += __shfl_xor(q2, 2); q2 += __shfl_xor(q2, 4); q2 += __shfl_xor(q2, 8);
        if (l15 == 0){
          int o = obase + m*16 + lh*4 + r;
          atomicAdd(psum + slot*OC + o, s);
          atomicAdd(psum + 64*OC + slot*OC + o, q2);
        }
      }
    }
  }

  if constexpr (POOL){
#pragma unroll
    for (int m = 0; m < MF; ++m){
      int o0 = obase + m*16 + lh*4;
      f32x4 gmx0, gmx1, gmn0, gmn1;
#pragma unroll
      for (int r = 0; r < 4; ++r){
        float v0 = acc[m][0][r], v1 = acc[m][1][r];
        float v2 = acc[m][2][r], v3 = acc[m][3][r];
        float ax0 = fmaxf(v0, v1), ax1 = fmaxf(v2, v3);
        float an0 = fminf(v0, v1), an1 = fminf(v2, v3);
#pragma unroll
        for (int mk = 1; mk < 16; mk <<= 1){
          ax0 = fmaxf(ax0, __shfl_xor(ax0, mk));
          ax1 = fmaxf(ax1, __shfl_xor(ax1, mk));
          an0 = fminf(an0, __shfl_xor(an0, mk));
          an1 = fminf(an1, __shfl_xor(an1, mk));
        }
        gmx0[r] = ax0; gmx1[r] = ax1; gmn0[r] = an0; gmn1[r] = an1;
      }
      if (l15 == 0){
        int gg = jbase >> 5;
        *(f32x4*)(rawmax + (size_t)gg*256 + o0)       = gmx0;
        *(f32x4*)(rawmax + (size_t)(gg + 1)*256 + o0) = gmx1;
        *(f32x4*)(rawmin + (size_t)gg*256 + o0)       = gmn0;
        *(f32x4*)(rawmin + (size_t)(gg + 1)*256 + o0) = gmn1;
      }
    }
  }

  if constexpr (STORE){
    __syncthreads();
#pragma unroll
    for (int m = 0; m < MF; ++m){
      int o0 = obase + m*16 + lh*4;
      int co = o0 >> 2;
#pragma unroll
      for (int n = 0; n < 4; ++n){
        int j = n*16 + l15;
        unsigned int w0 = f2bf(acc[m][n][0]) | ((unsigned int)f2bf(acc[m][n][1]) << 16);
        unsigned int w1 = f2bf(acc[m][n][2]) | ((unsigned int)f2bf(acc[m][n][3]) << 16);
        u32x2 pv = {w0, w1};
        *(u32x2*)&smem[j*OC + ((co ^ ((j & 15) << 1)) * 4)] = pv;
      }
    }
    __syncthreads();
    constexpr int CPR = OC / 4;
    constexpr int CPT = (64 * CPR) / 256;
#pragma unroll
    for (int q = 0; q < CPT; ++q){
      int ci = q*256 + t;
      int j = ci / CPR, co = ci % CPR;
      u32x2 v = *(const u32x2*)&smem[j*OC + ((co ^ ((j & 15) << 1)) * 4)];
      *(u32x2*)(Yout + (size_t)(jbase + j)*OC + co*4) = v;
    }
  }
}

// ---------------- 4-phase fps pipeline kernels (frozen R15) -----------------
#define LDSB (131072 + 2048 + 64)

template<int PH>
__global__ __launch_bounds__(1024)
void fps_phase(const float* __restrict__ xyz, const float* __restrict__ points,
               const float* __restrict__ W1, const float* __restrict__ W2,
               const float* __restrict__ W3,
               float* __restrict__ center_out, float* __restrict__ ddws,
               float* __restrict__ xs, float* __restrict__ ys,
               float* __restrict__ zs, float* __restrict__ pps,
               unsigned short* __restrict__ Wbf,
               unsigned short* __restrict__ pointsbf,
               int* __restrict__ kidx,
               const float* __restrict__ b1,
               unsigned short* __restrict__ Y1, float* __restrict__ psumA)
{
  __shared__ __attribute__((aligned(16))) char lds[LDSB];
  int t = threadIdx.x;
  if (blockIdx.x < BB){
    constexpr int g0 = (PH == 0) ? 1 : PH*128;
    constexpr int g1 = (PH + 1)*128;
    fps_part(xyz, center_out, ddws, blockIdx.x, t, g0, g1, PH < 3, lds);
    return;
  }
  if constexpr (PH == 0){
#pragma clang fp contract(off)
    int pb = blockIdx.x - BB;
    size_t i = ((size_t)pb*1024 + t)*8;
    f32x4 u0 = *(const f32x4*)(points + i);
    f32x4 u1 = *(const f32x4*)(points + i + 4);
    unsigned int w0 = f2bf(u0[0]) | ((unsigned int)f2bf(u0[1]) << 16);
    unsigned int w1 = f2bf(u0[2]) | ((unsigned int)f2bf(u0[3]) << 16);
    unsigned int w2 = f2bf(u1[0]) | ((unsigned int)f2bf(u1[1]) << 16);
    unsigned int w3 = f2bf(u1[2]) | ((unsigned int)f2bf(u1[3]) << 16);
    u32x4 pv = {w0, w1, w2, w3};
    *(u32x4*)(pointsbf + i) = pv;
    if (pb < 128){
      int n = pb*1024 + t;
      float x = xyz[(size_t)n*3 + 0];
      float y = xyz[(size_t)n*3 + 1];
      float z = xyz[(size_t)n*3 + 2];
      xs[n] = x; ys[n] = y; zs[n] = z;
      pps[n] = (x*x + y*y) + z*z;
    }
    if (pb < 64){
      int n = pb*1024 + t;
      float v;
      if (n < 16384)      v = W1[n];
      else if (n < 32768) v = W2[n - 16384];
      else                v = W3[n - 32768];
      Wbf[n] = f2bf(v);
    }
  } else {
    int pb = blockIdx.x - BB;
    if (pb < 256){
      unsigned long long (*kwl)[2][KK] = (unsigned long long(*)[2][KK])lds;
      int* kout = (int*)(lds + 8*2*KK*8);
      int sub = t >> 7, t128 = t & 127;
      int idx = pb*8 + sub;                   // 0..2047
      int b = idx >> 7, g = (PH-1)*128 + (idx & 127);
      knn_group(b*GG + g, t128, xs, ys, zs, pps, center_out, kidx,
                &kwl[sub][0], kout + sub*KK);
    } else if constexpr (PH >= 2){
      int hb = pb - 256;                      // 0..255
      int sub = t >> 8, t256 = t & 255;
      int u = hb*4 + sub;                     // 0..1023
      int us = (u & 7) * 128 + (u >> 3);      // bijective [0,1024)
      int b = us >> 6, tau = (PH-2)*64 + (us & 63);
      int sbid = b*256 + tau;
      unsigned short* smem = (unsigned short*)(lds + sub*16384);
      gemm_body<128, 0, true, true, false>(sbid, t256,
          Wbf, b1, pointsbf, kidx, nullptr, nullptr, nullptr, nullptr,
          Y1, psumA, nullptr, nullptr, smem, nullptr, nullptr);
    }
  }
}

// ---------------- tail: knn[384,512) 1-wave [bid<512] + gemm1 tau[128,192) --
__global__ __launch_bounds__(256)
void knn_gemm_tail(const float* __restrict__ xs, const float* __restrict__ ys,
                   const float* __restrict__ zs, const float* __restrict__ pps,
                   const float* __restrict__ center, int* __restrict__ kidx,
                   const unsigned short* __restrict__ Wbf,
                   const float* __restrict__ b1,
                   const unsigned short* __restrict__ pointsbf,
                   unsigned short* __restrict__ Y1, float* __restrict__ psumA)
{
  __shared__ unsigned short smem[64 * 128];
  int bid = blockIdx.x, t = threadIdx.x;
  if (bid < 512){
    // 4 independent 1-wave knn groups per block (no LDS, no barriers)
    int swz = (bid & 7) * 64 + (bid >> 3);    // bijective [0,512)
    int sub = t >> 6, lane = t & 63;
    int idx = swz*4 + sub;                    // 0..2047
    int b = idx >> 7, g = 384 + (idx & 127);
    knn_group1(b*GG + g, lane, xs, ys, zs, pps, center, kidx);
    return;
  }
  int h = bid - 512;
  int hs = (h & 7) * 128 + (h >> 3);          // bijective [0,1024)
  int b = hs >> 6, tau = 128 + (hs & 63);
  gemm_body<128, 0, true, true, false>(b*256 + tau, t,
      Wbf, b1, pointsbf, kidx, nullptr, nullptr, nullptr, nullptr,
      Y1, psumA, nullptr, nullptr, smem, nullptr, nullptr);
}

// ---------------- gemm1d: tiles tau in [192,256) ----------------------------
__global__ __launch_bounds__(256)
void gemm1d_kernel(const unsigned short* __restrict__ Wbf, const float* __restrict__ b1,
                   const unsigned short* __restrict__ pointsbf,
                   const int* __restrict__ kidx,
                   unsigned short* __restrict__ Y1, float* __restrict__ psumA)
{
  __shared__ unsigned short smem[64 * 128];
  int bid = blockIdx.x, t = threadIdx.x;
  int hs = (bid & 7) * 128 + (bid >> 3);
  int b = hs >> 6, tau = 192 + (hs & 63);
  gemm_body<128, 0, true, true, false>(b*256 + tau, t,
      Wbf, b1, pointsbf, kidx, nullptr, nullptr, nullptr, nullptr,
      Y1, psumA, nullptr, nullptr, smem, nullptr, nullptr);
}

// ---------------- full-grid gemm wrapper ------------------------------------
template<int OC, int MODE, bool STATS, bool STORE, bool POOL>
__global__ __launch_bounds__(256)
void gemm_kernel(const unsigned short* __restrict__ Wbf, const float* __restrict__ bias,
                 const unsigned short* __restrict__ Xin,
                 const float* __restrict__ psum_in, const float* __restrict__ gin,
                 const float* __restrict__ bein,
                 unsigned short* __restrict__ Yout, float* __restrict__ psum,
                 float* __restrict__ rawmax, float* __restrict__ rawmin)
{
  __shared__ unsigned short smem[64 * OC];
  __shared__ float ssc[128], ssh[128];
  int bid = blockIdx.x, t = threadIdx.x;
  int sbid = (bid & 7) * 512 + (bid >> 3);
  gemm_body<OC, MODE, STATS, STORE, POOL>(sbid, t,
      Wbf, bias, nullptr, nullptr, Xin, psum_in, gin, bein,
      Yout, psum, rawmax, rawmin, smem, ssc, ssh);
}

// ---------------- finish layer 3 --------------------------------------------
__global__ __launch_bounds__(256)
void finish3_kernel(const float* __restrict__ psumC, const float* __restrict__ g3,
                    const float* __restrict__ be3, const float* __restrict__ rawmax,
                    const float* __restrict__ rawmin, float* __restrict__ opool)
{
  __shared__ float ssc[256], ssh[256];
  int t = threadIdx.x;
  {
    float s = 0.f, q = 0.f;
#pragma unroll
    for (int sl = 0; sl < 64; ++sl){
      s += psumC[sl*256 + t];
      q += psumC[64*256 + sl*256 + t];
    }
    const float inv = 1.f / 262144.f;
    float mean = s * inv;
    float var  = q * inv - mean*mean;
    float sc = g3[t] * rsqrtf(var + 1e-5f);
    ssc[t] = sc;
    ssh[t] = be3[t] - mean*sc;
  }
  __syncthreads();
  float sc = ssc[t], sh = ssh[t];
  int gg0 = blockIdx.x * 16;
#pragma unroll
  for (int i = 0; i < 16; ++i){
    int gg = gg0 + i;
    float rv = (sc >= 0.f) ? rawmax[(size_t)gg*256 + t] : rawmin[(size_t)gg*256 + t];
    opool[(size_t)gg*256 + t] = fmaxf(fmaf(rv, sc, sh), 0.f);
  }
}

// ---------------- launch ----------------------------------------------------
extern "C" void kernel_launch(void* const* d_in, const int* in_sizes, int n_in,
                              void* d_out, int out_size, void* d_ws, size_t ws_size,
                              hipStream_t stream)
{
  const float* xyz    = (const float*)d_in[0];
  const float* points = (const float*)d_in[1];
  const float* W1  = (const float*)d_in[2];
  const float* b1  = (const float*)d_in[3];
  const float* g1  = (const float*)d_in[4];
  const float* be1 = (const float*)d_in[5];
  const float* W2  = (const float*)d_in[6];
  const float* b2  = (const float*)d_in[7];
  const float* g2  = (const float*)d_in[8];
  const float* be2 = (const float*)d_in[9];
  const float* W3  = (const float*)d_in[10];
  const float* b3  = (const float*)d_in[11];
  const float* g3  = (const float*)d_in[12];
  const float* be3 = (const float*)d_in[13];

  float* out    = (float*)d_out;
  float* center = out;                      // [B,G,3]
  float* opool  = out + (size_t)BB*GG*3;    // [B,G,256]

  char* ws = (char*)d_ws;
  size_t off = 0;
  auto alloc = [&](size_t bytes) -> void* {
    void* p = ws + off;
    off += (bytes + 255) & ~(size_t)255;
    return p;
  };
  unsigned short* Y1   = (unsigned short*)alloc((size_t)262144*128*2);
  unsigned short* Y2   = (unsigned short*)alloc((size_t)262144*128*2);
  int*   kidx = (int*)  alloc((size_t)262144*4);
  unsigned short* Wbf = (unsigned short*)alloc((size_t)65536*2);
  float* rawmax = (float*)alloc((size_t)8192*256*4);
  float* rawmin = (float*)alloc((size_t)8192*256*4);
  float* psumA = (float*)alloc((size_t)2*64*128*4);
  float* psumB = (float*)alloc((size_t)2*64*128*4);
  float* psumC = (float*)alloc((size_t)2*64*256*4);
  float* xsb  = (float*)alloc((size_t)131072*4);
  float* ysb  = (float*)alloc((size_t)131072*4);
  float* zsb  = (float*)alloc((size_t)131072*4);
  float* ppsb = (float*)alloc((size_t)131072*4);
  float* ddws = (float*)alloc((size_t)16*1024*8*4);
  unsigned short* pointsbf = Y2;            // aliases Y2; consumed before Y2 write

  hipMemsetAsync(psumA, 0, (size_t)(2*64*128 + 2*64*128 + 2*64*256)*4 + 1024, stream);

  fps_phase<0><<<BB + 2048, 1024, 0, stream>>>(
      xyz, points, W1, W2, W3, center, ddws, xsb, ysb, zsb, ppsb,
      Wbf, pointsbf, kidx, b1, Y1, psumA);
  fps_phase<1><<<BB + 256, 1024, 0, stream>>>(
      xyz, points, W1, W2, W3, center, ddws, xsb, ysb, zsb, ppsb,
      Wbf, pointsbf, kidx, b1, Y1, psumA);
  fps_phase<2><<<BB + 256 + 256, 1024, 0, stream>>>(
      xyz, points, W1, W2, W3, center, ddws, xsb, ysb, zsb, ppsb,
      Wbf, pointsbf, kidx, b1, Y1, psumA);
  fps_phase<3><<<BB + 256 + 256, 1024, 0, stream>>>(
      xyz, points, W1, W2, W3, center, ddws, xsb, ysb, zsb, ppsb,
      Wbf, pointsbf, kidx, b1, Y1, psumA);

  // tail: knn[384,512) (1-wave x4 per block) overlapped with gemm1 tau[128,192)
  knn_gemm_tail<<<1536, 256, 0, stream>>>(
      xsb, ysb, zsb, ppsb, center, kidx, Wbf, b1, pointsbf, Y1, psumA);
  gemm1d_kernel<<<1024, 256, 0, stream>>>(Wbf, b1, pointsbf, kidx, Y1, psumA);

  gemm_kernel<128, 1, true, true, false><<<4096, 256, 0, stream>>>(
      Wbf + 16384, b2, Y1, psumA, g1, be1, Y2, psumB, nullptr, nullptr);

  gemm_kernel<256, 1, true, false, true><<<4096, 256, 0, stream>>>(
      Wbf + 32768, b3, Y2, psumB, g2, be2, nullptr, psumC, rawmax, rawmin);

  finish3_kernel<<<512, 256, 0, stream>>>(psumC, g3, be3, rawmax, rawmin, opool);
}

// Round 17
// 719.531 us; speedup vs baseline: 1.0469x; 1.0469x over previous
//
#include <hip/hip_runtime.h>
#include <hip/hip_bf16.h>

#define BB 16
#define NN 8192
#define GG 512
#define KK 32
#define DD 128

typedef __attribute__((ext_vector_type(8))) short bf16x8;
typedef __attribute__((ext_vector_type(4))) float f32x4;
typedef __attribute__((ext_vector_type(2))) float f32x2;
typedef __attribute__((ext_vector_type(2))) unsigned int u32x2;
typedef __attribute__((ext_vector_type(4))) unsigned int u32x4;
typedef __attribute__((ext_vector_type(2))) unsigned long long u64x2;

__device__ __forceinline__ unsigned short f2bf(float f){
  unsigned int u = __builtin_bit_cast(unsigned int, f);
  unsigned int r = (u + 0x7FFFu + ((u >> 16) & 1u)) >> 16;
  return (unsigned short)r;
}
__device__ __forceinline__ float bf2f(unsigned short h){
  unsigned int u = ((unsigned int)h) << 16;
  return __builtin_bit_cast(float, u);
}

// DPP wave64 reductions: row_shr 1/2/4/8 then row_bcast15/31; result in lane 63.
__device__ __forceinline__ float wave_max_f32(float v){
  int x = __builtin_bit_cast(int, v);
#define STEPMAX(C) { int y = __builtin_amdgcn_update_dpp(x, x, C, 0xF, 0xF, false); \
  float f = fmaxf(__builtin_bit_cast(float,x), __builtin_bit_cast(float,y)); x = __builtin_bit_cast(int,f); }
  STEPMAX(0x111) STEPMAX(0x112) STEPMAX(0x114) STEPMAX(0x118) STEPMAX(0x142) STEPMAX(0x143)
#undef STEPMAX
  return __builtin_bit_cast(float, __builtin_amdgcn_readlane(x, 63));
}
__device__ __forceinline__ float wave_min_f32(float v){
  int x = __builtin_bit_cast(int, v);
#define STEPMIN(C) { int y = __builtin_amdgcn_update_dpp(x, x, C, 0xF, 0xF, false); \
  float f = fminf(__builtin_bit_cast(float,x), __builtin_bit_cast(float,y)); x = __builtin_bit_cast(int,f); }
  STEPMIN(0x111) STEPMIN(0x112) STEPMIN(0x114) STEPMIN(0x118) STEPMIN(0x142) STEPMIN(0x143)
#undef STEPMIN
  return __builtin_bit_cast(float, __builtin_amdgcn_readlane(x, 63));
}
__device__ __forceinline__ int wave_min_i32(int v){
  int x = v;
#define STEPMNI(C) { int y = __builtin_amdgcn_update_dpp(x, x, C, 0xF, 0xF, false); \
  x = (y < x) ? y : x; }
  STEPMNI(0x111) STEPMNI(0x112) STEPMNI(0x114) STEPMNI(0x118) STEPMNI(0x142) STEPMNI(0x143)
#undef STEPMNI
  return __builtin_amdgcn_readlane(x, 63);
}

// ---------------- KNN 2-wave group worker (frozen R13) ----------------------
__device__ __forceinline__ void knn_group(int bg, int t128,
    const float* __restrict__ xs, const float* __restrict__ ys,
    const float* __restrict__ zs, const float* __restrict__ pps,
    const float* __restrict__ center, int* __restrict__ kidx,
    unsigned long long (*wlist)[KK], int* outidx)
{
#pragma clang fp contract(off)
  int lane = t128 & 63, w = t128 >> 6;
  int b = bg >> 9;
  const float cx = center[(size_t)bg*3+0];
  const float cy = center[(size_t)bg*3+1];
  const float cz = center[(size_t)bg*3+2];
  const float ccv = (cx*cx + cy*cy) + cz*cz;   // same expr tree as ref cc
  const float* xb = xs  + (size_t)b*NN;
  const float* yb = ys  + (size_t)b*NN;
  const float* zb = zs  + (size_t)b*NN;
  const float* pb = pps + (size_t)b*NN;

  f32x2 d2v[32];
  float gmin[8]; int gidx[8];
#pragma unroll
  for (int gi = 0; gi < 8; ++gi){ gmin[gi] = 3.4e38f; gidx[gi] = 0x7FFFFFFF; }
  int nb = w*128 + 2*lane;
  f32x2 cxv = (f32x2){cx, cx}, cyv = (f32x2){cy, cy}, czv = (f32x2){cz, cz};
  f32x2 ccvv = (f32x2){ccv, ccv};
#pragma unroll
  for (int q = 0; q < 32; ++q){
    int n0 = q*256 + nb;
    f32x2 x = *(const f32x2*)(xb + n0);
    f32x2 y = *(const f32x2*)(yb + n0);
    f32x2 z = *(const f32x2*)(zb + n0);
    f32x2 pp = *(const f32x2*)(pb + n0);
    f32x2 dot = (cxv*x + cyv*y) + czv*z;
    f32x2 d = (ccvv + pp) - 2.0f*dot;
    d2v[q] = d;
    int gi = q >> 2;
    if (d.x < gmin[gi]){ gmin[gi] = d.x; gidx[gi] = n0; }
    if (d.y < gmin[gi]){ gmin[gi] = d.y; gidx[gi] = n0 + 1; }
  }
  float bv = gmin[0]; int bi = gidx[0];
#pragma unroll
  for (int gi = 1; gi < 8; ++gi)
    if (gmin[gi] < bv){ bv = gmin[gi]; bi = gidx[gi]; }

  unsigned long long mykey = ~0ULL;
  for (int k = 0; k < KK; ++k){
    float wmin = wave_min_f32(bv);
    unsigned long long mask = __ballot(bv == wmin);
    int n_win;
    if (__popcll(mask) == 1){
      n_win = __builtin_amdgcn_readlane(bi, (int)__builtin_ctzll(mask));
    } else {
      int cand = (bv == wmin) ? bi : 0x7FFFFFFF;
      n_win = wave_min_i32(cand);
    }
    if (lane == k){
      unsigned int fm = __builtin_bit_cast(unsigned int, wmin);
      unsigned int mapd = fm ^ (unsigned int)(((int)fm >> 31) | 0x80000000);
      mykey = ((unsigned long long)mapd << 32) | (unsigned int)n_win;
    }
    if (bi == n_win){                     // owner lane only
#define RESCAN2(GI) { \
      float nm = 3.4e38f; int ni = 0x7FFFFFFF; \
      _Pragma("unroll") \
      for (int j = 0; j < 4; ++j){ \
        int q = GI*4 + j; \
        int n0 = q*256 + nb; \
        f32x2 v = d2v[q]; \
        if (n0 == n_win) v.x = 3.4e38f; \
        if (n0 + 1 == n_win) v.y = 3.4e38f; \
        d2v[q] = v; \
        if (v.x < nm){ nm = v.x; ni = n0; } \
        if (v.y < nm){ nm = v.y; ni = n0 + 1; } } \
      gmin[GI] = nm; gidx[GI] = ni; }
      switch (n_win >> 10){
        case 0: RESCAN2(0); break;
        case 1: RESCAN2(1); break;
        case 2: RESCAN2(2); break;
        case 3: RESCAN2(3); break;
        case 4: RESCAN2(4); break;
        case 5: RESCAN2(5); break;
        case 6: RESCAN2(6); break;
        default: RESCAN2(7); break;
      }
#undef RESCAN2
      bv = gmin[0]; bi = gidx[0];
#pragma unroll
      for (int gi = 1; gi < 8; ++gi)
        if (gmin[gi] < bv){ bv = gmin[gi]; bi = gidx[gi]; }
    }
  }

  if (lane < KK) wlist[w][lane] = mykey;
  __syncthreads();
  if (lane < KK){
    unsigned long long K = mykey;
    const unsigned long long* other = wlist[1 - w];
    int cnt = 0;
#pragma unroll
    for (int j = 0; j < KK; ++j) cnt += (other[j] < K) ? 1 : 0;
    int rank = lane + cnt;
    if (rank < KK) outidx[rank] = (int)(unsigned int)K;
  }
  __syncthreads();
  if (t128 < KK) kidx[(size_t)bg*KK + t128] = outidx[t128];
}

// ---------------- FPS slice (frozen R15) ------------------------------------
__device__ __forceinline__ void fps_part(const float* __restrict__ xyz,
    float* __restrict__ center_out, float* __restrict__ ddws,
    int b, int t, int g0, int g1, bool save_dd, char* lds)
{
#pragma clang fp contract(off)
  float (*tbl)[4]    = (float(*)[4])lds;                       // 128 KB
  float (*outbuf)[4] = (float(*)[4])(lds + 131072);            // 2 KB
  unsigned long long (*slot)[2] =
      (unsigned long long(*)[2])(lds + 131072 + 2048);         // 48 B
  int lane = t & 63, wid = t >> 6;
  const float* base = xyz + (size_t)b * NN * 3;
  f32x2 px[4], py[4], pz[4], dd[4];
  if (g0 == 1){
#pragma unroll
    for (int i = 0; i < 4; ++i) dd[i] = (f32x2){1e10f, 1e10f};
  } else {
    const float* dp = ddws + ((size_t)b*1024 + t)*8;
    f32x4 s0 = *(const f32x4*)dp;
    f32x4 s1 = *(const f32x4*)(dp + 4);
    dd[0] = (f32x2){s0[0], s0[1]};
    dd[1] = (f32x2){s0[2], s0[3]};
    dd[2] = (f32x2){s1[0], s1[1]};
    dd[3] = (f32x2){s1[2], s1[3]};
  }
#pragma unroll
  for (int i = 0; i < 4; ++i){
    int n0 = i*2048 + t, n1 = n0 + 1024;
    float x0 = base[n0*3+0], y0 = base[n0*3+1], z0 = base[n0*3+2];
    float x1 = base[n1*3+0], y1 = base[n1*3+1], z1 = base[n1*3+2];
    px[i] = (f32x2){x0, x1}; py[i] = (f32x2){y0, y1}; pz[i] = (f32x2){z0, z1};
    f32x4 c0 = {x0, y0, z0, 0.f}, c1 = {x1, y1, z1, 0.f};
    *(f32x4*)&tbl[n0][0] = c0;
    *(f32x4*)&tbl[n1][0] = c1;
  }
  float lx, ly, lz;
  if (g0 == 1){ lx = base[0]; ly = base[1]; lz = base[2]; }
  else {
    lx = center_out[((size_t)b*GG + g0 - 1)*3 + 0];
    ly = center_out[((size_t)b*GG + g0 - 1)*3 + 1];
    lz = center_out[((size_t)b*GG + g0 - 1)*3 + 2];
  }
  if (t < 6) slot[t >> 1][t & 1] = 0;
  __syncthreads();
  for (int g = g0; g < g1; ++g){
    f32x2 lxv = (f32x2){lx, lx}, lyv = (f32x2){ly, ly}, lzv = (f32x2){lz, lz};
    f32x2 vm = (f32x2){-1.f, -1.f};
#pragma unroll
    for (int i = 0; i < 4; ++i){
      f32x2 dx = px[i] - lxv, dy = py[i] - lyv, dz = pz[i] - lzv;
      f32x2 s = (dx*dx + dy*dy) + dz*dz;
      f32x2 nd = __builtin_elementwise_min(dd[i], s);
      dd[i] = nd;
      vm = __builtin_elementwise_max(vm, nd);
    }
    float m = fmaxf(vm.x, vm.y);
    int mi = 0x7FFFFFFF;
#pragma unroll
    for (int i = 3; i >= 0; --i){
      int n0 = i*2048 + t;
      if (dd[i].y == m) mi = n0 + 1024;
      if (dd[i].x == m) mi = n0;
    }
    float wmax = wave_max_f32(m);
    bool cnd = (m == wmax);
    unsigned long long mask = __ballot(cnd);
    int n_wave;
    if (__popcll(mask) == 1){
      n_wave = __builtin_amdgcn_readlane(mi, (int)__builtin_ctzll(mask));
    } else {
      int cand = cnd ? mi : 0x7FFFFFFF;
      n_wave = wave_min_i32(cand);
    }
    unsigned long long key =
        ((unsigned long long)__builtin_bit_cast(unsigned int, wmax) << 32)
      | (unsigned int)(~n_wave);
    int p = g - (g/3)*3;                             // g % 3
    if (lane == 0) atomicMax(&slot[p][wid & 1], key);
    __syncthreads();
    u64x2 sA = *(const u64x2*)&slot[p][0];
    unsigned long long M = sA.x > sA.y ? sA.x : sA.y;
    int n_win = (int)~((unsigned int)M);
    f32x4 cw = *(const f32x4*)&tbl[n_win][0];
    lx = cw[0]; ly = cw[1]; lz = cw[2];
    if (t == 0) *(f32x4*)&outbuf[g - g0][0] = cw;
    if (t < 2){
      int z = p + 2; if (z >= 3) z -= 3;             // (g+2) % 3
      slot[z][t] = 0;
    }
  }
  __syncthreads();
  if (t < g1 - g0){
    int g = g0 + t;
    center_out[((size_t)b*GG + g)*3 + 0] = outbuf[t][0];
    center_out[((size_t)b*GG + g)*3 + 1] = outbuf[t][1];
    center_out[((size_t)b*GG + g)*3 + 2] = outbuf[t][2];
  }
  if (g0 == 1 && t == 0){
    center_out[((size_t)b*GG)*3 + 0] = base[0];
    center_out[((size_t)b*GG)*3 + 1] = base[1];
    center_out[((size_t)b*GG)*3 + 2] = base[2];
  }
  if (save_dd){
    f32x4 s0 = {dd[0].x, dd[0].y, dd[1].x, dd[1].y};
    f32x4 s1 = {dd[2].x, dd[2].y, dd[3].x, dd[3].y};
    float* dp = ddws + ((size_t)b*1024 + t)*8;
    *(f32x4*)dp       = s0;
    *(f32x4*)(dp + 4) = s1;
  }
}

// ---------------- GEMM body (frozen R14) ------------------------------------
template<int OC, int MODE, bool STATS, bool STORE, bool POOL>
__device__ __forceinline__ void gemm_body(int sbid, int t,
    const unsigned short* __restrict__ Wbf, const float* __restrict__ bias,
    const unsigned short* __restrict__ pointsbf, const int* __restrict__ kidx,
    const unsigned short* __restrict__ Xin,
    const float* __restrict__ psum_in, const float* __restrict__ gin,
    const float* __restrict__ bein,
    unsigned short* __restrict__ Yout, float* __restrict__ psum,
    float* __restrict__ rawmax, float* __restrict__ rawmin,
    unsigned short* smem, float* ssc, float* ssh)
{
  constexpr int MF = OC / 64;
  int l = t & 63, w = t >> 6;
  int l15 = l & 15, lh = l >> 4;
  int jbase = sbid * 64;
  int obase = w * (OC / 4);
  int slot = sbid & 63;

  if constexpr (MODE == 1){
    if (t < 128){
      float s = 0.f, q = 0.f;
#pragma unroll
      for (int sl = 0; sl < 64; ++sl){
        s += psum_in[sl*128 + t];
        q += psum_in[64*128 + sl*128 + t];
      }
      const float inv = 1.f / 262144.f;    // B*K*G
      float mean = s * inv;
      float var  = q * inv - mean*mean;
      float sc = gin[t] * rsqrtf(var + 1e-5f);
      ssc[t] = sc;
      ssh[t] = bein[t] - mean*sc;
    }
  }

  bf16x8 a[MF][4];
#pragma unroll
  for (int m = 0; m < MF; ++m)
#pragma unroll
    for (int kf = 0; kf < 4; ++kf){
      int row = obase + m*16 + l15;
      int c8  = kf*32 + lh*8;
      a[m][kf] = *(const bf16x8*)(Wbf + (size_t)row*128 + c8);
    }

  if constexpr (MODE == 1) __syncthreads();

#pragma unroll
  for (int q = 0; q < 4; ++q){
    int ci = q*256 + t;
    int j = ci >> 4, cc = ci & 15;
    unsigned short* dst = &smem[j*128 + ((cc ^ (j & 15)) * 8)];
    if constexpr (MODE == 0){
      int jg = jbase + j;
      int bb = jg >> 14;
      int row = kidx[jg];
      const unsigned short* src = pointsbf + ((size_t)bb*NN + row)*DD + cc*8;
      *(u32x4*)dst = *(const u32x4*)src;
    } else {
      const unsigned short* src = Xin + ((size_t)(jbase + j))*128 + cc*8;
      u32x4 v = *(const u32x4*)src;
      int c0 = cc * 8;
      unsigned int wo[4];
#pragma unroll
      for (int p = 0; p < 4; ++p){
        float x0 = bf2f((unsigned short)(v[p] & 0xFFFFu));
        float x1 = bf2f((unsigned short)(v[p] >> 16));
        x0 = fmaxf(fmaf(x0, ssc[c0 + 2*p],     ssh[c0 + 2*p]),     0.f);
        x1 = fmaxf(fmaf(x1, ssc[c0 + 2*p + 1], ssh[c0 + 2*p + 1]), 0.f);
        wo[p] = f2bf(x0) | ((unsigned int)f2bf(x1) << 16);
      }
      u32x4 pv = {wo[0], wo[1], wo[2], wo[3]};
      *(u32x4*)dst = pv;
    }
  }
  __syncthreads();

  f32x4 acc[MF][4];
#pragma unroll
  for (int m = 0; m < MF; ++m)
#pragma unroll
    for (int n = 0; n < 4; ++n)
      acc[m][n] = (f32x4){0.f, 0.f, 0.f, 0.f};

#pragma unroll
  for (int n = 0; n < 4; ++n){
    bf16x8 bfr[4];
    int j = n*16 + l15;
#pragma unroll
    for (int kf = 0; kf < 4; ++kf){
      int ch = kf*4 + lh;
      bfr[kf] = *(const bf16x8*)&smem[j*128 + ((ch ^ (j & 15)) * 8)];
    }
#pragma unroll
    for (int m = 0; m < MF; ++m)
#pragma unroll
      for (int kf = 0; kf < 4; ++kf)
        acc[m][n] = __builtin_amdgcn_mfma_f32_16x16x32_bf16(a[m][kf], bfr[kf], acc[m][n], 0, 0, 0);
  }

#pragma unroll
  for (int m = 0; m < MF; ++m){
    int o0 = obase + m*16 + lh*4;
    f32x4 bv = *(const f32x4*)(bias + o0);
#pragma unroll
    for (int n = 0; n < 4; ++n) acc[m][n] += bv;
  }

  if constexpr (STATS){
#pragma unroll
    for (int m = 0; m < MF; ++m){
#pragma unroll
      for (int r = 0; r < 4; ++r){
        float s = 0.f, q2 = 0.f;
#pragma unroll
        for (int n = 0; n < 4; ++n){ float v = acc[m][n][r]; s += v; q2 += v*v; }
        s  += __shfl_xor(s, 1);  s  += __shfl_xor(s, 2);  s  += __shfl_xor(s, 4);  s  += __shfl_xor(s, 8);
        q2 += __shfl_xor(q2, 1); q2 += __shfl_xor(q2, 2); q2 += __shfl_xor(q2, 4); q2 += __shfl_xor(q2, 8);
        if (l15 == 0){
          int o = obase + m*16 + lh*4 + r;
          atomicAdd(psum + slot*OC + o, s);
          atomicAdd(psum + 64*OC + slot*OC + o, q2);
        }
      }
    }
  }

  if constexpr (POOL){
#pragma unroll
    for (int m = 0; m < MF; ++m){
      int o0 = obase + m*16 + lh*4;
      f32x4 gmx0, gmx1, gmn0, gmn1;
#pragma unroll
      for (int r = 0; r < 4; ++r){
        float v0 = acc[m][0][r], v1 = acc[m][1][r];
        float v2 = acc[m][2][r], v3 = acc[m][3][r];
        float ax0 = fmaxf(v0, v1), ax1 = fmaxf(v2, v3);
        float an0 = fminf(v0, v1), an1 = fminf(v2, v3);
#pragma unroll
        for (int mk = 1; mk < 16; mk <<= 1){
          ax0 = fmaxf(ax0, __shfl_xor(ax0, mk));
          ax1 = fmaxf(ax1, __shfl_xor(ax1, mk));
          an0 = fminf(an0, __shfl_xor(an0, mk));
          an1 = fminf(an1, __shfl_xor(an1, mk));
        }
        gmx0[r] = ax0; gmx1[r] = ax1; gmn0[r] = an0; gmn1[r] = an1;
      }
      if (l15 == 0){
        int gg = jbase >> 5;
        *(f32x4*)(rawmax + (size_t)gg*256 + o0)       = gmx0;
        *(f32x4*)(rawmax + (size_t)(gg + 1)*256 + o0) = gmx1;
        *(f32x4*)(rawmin + (size_t)gg*256 + o0)       = gmn0;
        *(f32x4*)(rawmin + (size_t)(gg + 1)*256 + o0) = gmn1;
      }
    }
  }

  if constexpr (STORE){
    __syncthreads();
#pragma unroll
    for (int m = 0; m < MF; ++m){
      int o0 = obase + m*16 + lh*4;
      int co = o0 >> 2;
#pragma unroll
      for (int n = 0; n < 4; ++n){
        int j = n*16 + l15;
        unsigned int w0 = f2bf(acc[m][n][0]) | ((unsigned int)f2bf(acc[m][n][1]) << 16);
        unsigned int w1 = f2bf(acc[m][n][2]) | ((unsigned int)f2bf(acc[m][n][3]) << 16);
        u32x2 pv = {w0, w1};
        *(u32x2*)&smem[j*OC + ((co ^ ((j & 15) << 1)) * 4)] = pv;
      }
    }
    __syncthreads();
    constexpr int CPR = OC / 4;
    constexpr int CPT = (64 * CPR) / 256;
#pragma unroll
    for (int q = 0; q < CPT; ++q){
      int ci = q*256 + t;
      int j = ci / CPR, co = ci % CPR;
      u32x2 v = *(const u32x2*)&smem[j*OC + ((co ^ ((j & 15) << 1)) * 4)];
      *(u32x2*)(Yout + (size_t)(jbase + j)*OC + co*4) = v;
    }
  }
}

// ---------------- 5-phase fps pipeline --------------------------------------
#define LDSB (131072 + 2048 + 64)

template<int PH>
__global__ __launch_bounds__(1024)
void fps_phase(const float* __restrict__ xyz, const float* __restrict__ points,
               const float* __restrict__ W1, const float* __restrict__ W2,
               const float* __restrict__ W3,
               float* __restrict__ center_out, float* __restrict__ ddws,
               float* __restrict__ xs, float* __restrict__ ys,
               float* __restrict__ zs, float* __restrict__ pps,
               unsigned short* __restrict__ Wbf,
               unsigned short* __restrict__ pointsbf,
               int* __restrict__ kidx,
               const float* __restrict__ b1,
               unsigned short* __restrict__ Y1, float* __restrict__ psumA)
{
  __shared__ __attribute__((aligned(16))) char lds[LDSB];
  int t = threadIdx.x;
  if (blockIdx.x < BB){
    constexpr int g0 = (PH == 0) ? 1 : (PH == 1 ? 128 : (PH == 2 ? 256 : (PH == 3 ? 384 : 448)));
    constexpr int g1 = (PH == 0) ? 128 : (PH == 1 ? 256 : (PH == 2 ? 384 : (PH == 3 ? 448 : 512)));
    fps_part(xyz, center_out, ddws, blockIdx.x, t, g0, g1, PH < 4, lds);
    return;
  }
  if constexpr (PH == 0){
#pragma clang fp contract(off)
    int pb = blockIdx.x - BB;
    size_t i = ((size_t)pb*1024 + t)*8;
    f32x4 u0 = *(const f32x4*)(points + i);
    f32x4 u1 = *(const f32x4*)(points + i + 4);
    unsigned int w0 = f2bf(u0[0]) | ((unsigned int)f2bf(u0[1]) << 16);
    unsigned int w1 = f2bf(u0[2]) | ((unsigned int)f2bf(u0[3]) << 16);
    unsigned int w2 = f2bf(u1[0]) | ((unsigned int)f2bf(u1[1]) << 16);
    unsigned int w3 = f2bf(u1[2]) | ((unsigned int)f2bf(u1[3]) << 16);
    u32x4 pv = {w0, w1, w2, w3};
    *(u32x4*)(pointsbf + i) = pv;
    if (pb < 128){
      int n = pb*1024 + t;
      float x = xyz[(size_t)n*3 + 0];
      float y = xyz[(size_t)n*3 + 1];
      float z = xyz[(size_t)n*3 + 2];
      xs[n] = x; ys[n] = y; zs[n] = z;
      pps[n] = (x*x + y*y) + z*z;
    }
    if (pb < 64){
      int n = pb*1024 + t;
      float v;
      if (n < 16384)      v = W1[n];
      else if (n < 32768) v = W2[n - 16384];
      else                v = W3[n - 32768];
      Wbf[n] = f2bf(v);
    }
  } else {
    int pb = blockIdx.x - BB;
    constexpr int KNB  = (PH == 4) ? 128 : 256;    // knn host blocks
    constexpr int KNG0 = (PH - 1) * 128;           // knn group start
    if (pb < KNB){
      unsigned long long (*kwl)[2][KK] = (unsigned long long(*)[2][KK])lds;
      int* kout = (int*)(lds + 8*2*KK*8);
      int sub = t >> 7, t128 = t & 127;
      int idx = pb*8 + sub;
      int b, g;
      if constexpr (PH == 4){ b = idx >> 6; g = 384 + (idx & 63); }   // 1024 groups
      else                  { b = idx >> 7; g = KNG0 + (idx & 127); } // 2048 groups
      knn_group(b*GG + g, t128, xs, ys, zs, pps, center_out, kidx,
                &kwl[sub][0], kout + sub*KK);
    } else if constexpr (PH >= 2){
      constexpr int TAU0 = (PH - 2) * 64;          // gemm1 tile start
      int hb = pb - KNB;                           // 0..255
      int sub = t >> 8, t256 = t & 255;
      int u = hb*4 + sub;                          // 0..1023
      int us = (u & 7) * 128 + (u >> 3);           // bijective [0,1024)
      int b = us >> 6, tau = TAU0 + (us & 63);
      unsigned short* smem = (unsigned short*)(lds + sub*16384);
      gemm_body<128, 0, true, true, false>(b*256 + tau, t256,
          Wbf, b1, pointsbf, kidx, nullptr, nullptr, nullptr, nullptr,
          Y1, psumA, nullptr, nullptr, smem, nullptr, nullptr);
    }
  }
}

// ---------------- tail: knn[448,512) 2-wave [bid<512] + gemm1 tau[192,224) --
__global__ __launch_bounds__(256)
void knn_gemm_tail(const float* __restrict__ xs, const float* __restrict__ ys,
                   const float* __restrict__ zs, const float* __restrict__ pps,
                   const float* __restrict__ center, int* __restrict__ kidx,
                   const unsigned short* __restrict__ Wbf,
                   const float* __restrict__ b1,
                   const unsigned short* __restrict__ pointsbf,
                   unsigned short* __restrict__ Y1, float* __restrict__ psumA)
{
  __shared__ unsigned short smem[64 * 128];
  __shared__ unsigned long long kwl[2][2][KK] __attribute__((aligned(16)));
  __shared__ int kout[2][KK];
  int bid = blockIdx.x, t = threadIdx.x;
  if (bid < 512){
    int swz = (bid & 7) * 64 + (bid >> 3);    // bijective [0,512)
    int sub = t >> 7, t128 = t & 127;
    int idx = swz*2 + sub;                    // 0..1023
    int b = idx >> 6, g = 448 + (idx & 63);
    knn_group(b*GG + g, t128, xs, ys, zs, pps, center, kidx,
              kwl[sub], kout[sub]);
    return;
  }
  int h = bid - 512;                          // 0..511
  int hs = (h & 7) * 64 + (h >> 3);           // bijective [0,512)
  int b = hs >> 5, tau = 192 + (hs & 31);
  gemm_body<128, 0, true, true, false>(b*256 + tau, t,
      Wbf, b1, pointsbf, kidx, nullptr, nullptr, nullptr, nullptr,
      Y1, psumA, nullptr, nullptr, smem, nullptr, nullptr);
}

// ---------------- gemm1e: tiles tau in [224,256) ----------------------------
__global__ __launch_bounds__(256)
void gemm1e_kernel(const unsigned short* __restrict__ Wbf, const float* __restrict__ b1,
                   const unsigned short* __restrict__ pointsbf,
                   const int* __restrict__ kidx,
                   unsigned short* __restrict__ Y1, float* __restrict__ psumA)
{
  __shared__ unsigned short smem[64 * 128];
  int bid = blockIdx.x, t = threadIdx.x;
  int hs = (bid & 7) * 64 + (bid >> 3);       // bijective [0,512)
  int b = hs >> 5, tau = 224 + (hs & 31);
  gemm_body<128, 0, true, true, false>(b*256 + tau, t,
      Wbf, b1, pointsbf, kidx, nullptr, nullptr, nullptr, nullptr,
      Y1, psumA, nullptr, nullptr, smem, nullptr, nullptr);
}

// ---------------- full-grid gemm wrapper ------------------------------------
template<int OC, int MODE, bool STATS, bool STORE, bool POOL>
__global__ __launch_bounds__(256)
void gemm_kernel(const unsigned short* __restrict__ Wbf, const float* __restrict__ bias,
                 const unsigned short* __restrict__ Xin,
                 const float* __restrict__ psum_in, const float* __restrict__ gin,
                 const float* __restrict__ bein,
                 unsigned short* __restrict__ Yout, float* __restrict__ psum,
                 float* __restrict__ rawmax, float* __restrict__ rawmin)
{
  __shared__ unsigned short smem[64 * OC];
  __shared__ float ssc[128], ssh[128];
  int bid = blockIdx.x, t = threadIdx.x;
  int sbid = (bid & 7) * 512 + (bid >> 3);
  gemm_body<OC, MODE, STATS, STORE, POOL>(sbid, t,
      Wbf, bias, nullptr, nullptr, Xin, psum_in, gin, bein,
      Yout, psum, rawmax, rawmin, smem, ssc, ssh);
}

// ---------------- finish layer 3 --------------------------------------------
__global__ __launch_bounds__(256)
void finish3_kernel(const float* __restrict__ psumC, const float* __restrict__ g3,
                    const float* __restrict__ be3, const float* __restrict__ rawmax,
                    const float* __restrict__ rawmin, float* __restrict__ opool)
{
  __shared__ float ssc[256], ssh[256];
  int t = threadIdx.x;
  {
    float s = 0.f, q = 0.f;
#pragma unroll
    for (int sl = 0; sl < 64; ++sl){
      s += psumC[sl*256 + t];
      q += psumC[64*256 + sl*256 + t];
    }
    const float inv = 1.f / 262144.f;
    float mean = s * inv;
    float var  = q * inv - mean*mean;
    float sc = g3[t] * rsqrtf(var + 1e-5f);
    ssc[t] = sc;
    ssh[t] = be3[t] - mean*sc;
  }
  __syncthreads();
  float sc = ssc[t], sh = ssh[t];
  int gg0 = blockIdx.x * 16;
#pragma unroll
  for (int i = 0; i < 16; ++i){
    int gg = gg0 + i;
    float rv = (sc >= 0.f) ? rawmax[(size_t)gg*256 + t] : rawmin[(size_t)gg*256 + t];
    opool[(size_t)gg*256 + t] = fmaxf(fmaf(rv, sc, sh), 0.f);
  }
}

// ---------------- launch ----------------------------------------------------
extern "C" void kernel_launch(void* const* d_in, const int* in_sizes, int n_in,
                              void* d_out, int out_size, void* d_ws, size_t ws_size,
                              hipStream_t stream)
{
  const float* xyz    = (const float*)d_in[0];
  const float* points = (const float*)d_in[1];
  const float* W1  = (const float*)d_in[2];
  const float* b1  = (const float*)d_in[3];
  const float* g1  = (const float*)d_in[4];
  const float* be1 = (const float*)d_in[5];
  const float* W2  = (const float*)d_in[6];
  const float* b2  = (const float*)d_in[7];
  const float* g2  = (const float*)d_in[8];
  const float* be2 = (const float*)d_in[9];
  const float* W3  = (const float*)d_in[10];
  const float* b3  = (const float*)d_in[11];
  const float* g3  = (const float*)d_in[12];
  const float* be3 = (const float*)d_in[13];

  float* out    = (float*)d_out;
  float* center = out;                      // [B,G,3]
  float* opool  = out + (size_t)BB*GG*3;    // [B,G,256]

  char* ws = (char*)d_ws;
  size_t off = 0;
  auto alloc = [&](size_t bytes) -> void* {
    void* p = ws + off;
    off += (bytes + 255) & ~(size_t)255;
    return p;
  };
  unsigned short* Y1   = (unsigned short*)alloc((size_t)262144*128*2);
  unsigned short* Y2   = (unsigned short*)alloc((size_t)262144*128*2);
  int*   kidx = (int*)  alloc((size_t)262144*4);
  unsigned short* Wbf = (unsigned short*)alloc((size_t)65536*2);
  float* rawmax = (float*)alloc((size_t)8192*256*4);
  float* rawmin = (float*)alloc((size_t)8192*256*4);
  float* psumA = (float*)alloc((size_t)2*64*128*4);
  float* psumB = (float*)alloc((size_t)2*64*128*4);
  float* psumC = (float*)alloc((size_t)2*64*256*4);
  float* xsb  = (float*)alloc((size_t)131072*4);
  float* ysb  = (float*)alloc((size_t)131072*4);
  float* zsb  = (float*)alloc((size_t)131072*4);
  float* ppsb = (float*)alloc((size_t)131072*4);
  float* ddws = (float*)alloc((size_t)16*1024*8*4);
  unsigned short* pointsbf = Y2;            // aliases Y2; consumed before Y2 write

  hipMemsetAsync(psumA, 0, (size_t)(2*64*128 + 2*64*128 + 2*64*256)*4 + 1024, stream);

  // P0: fps g[1,128) + prep
  fps_phase<0><<<BB + 2048, 1024, 0, stream>>>(
      xyz, points, W1, W2, W3, center, ddws, xsb, ysb, zsb, ppsb,
      Wbf, pointsbf, kidx, b1, Y1, psumA);
  // P1: fps g[128,256) + knn[0,128)
  fps_phase<1><<<BB + 256, 1024, 0, stream>>>(
      xyz, points, W1, W2, W3, center, ddws, xsb, ysb, zsb, ppsb,
      Wbf, pointsbf, kidx, b1, Y1, psumA);
  // P2: fps g[256,384) + knn[128,256) + gemm1 tau[0,64)
  fps_phase<2><<<BB + 512, 1024, 0, stream>>>(
      xyz, points, W1, W2, W3, center, ddws, xsb, ysb, zsb, ppsb,
      Wbf, pointsbf, kidx, b1, Y1, psumA);
  // P3: fps g[384,448) + knn[256,384) + gemm1 tau[64,128)
  fps_phase<3><<<BB + 512, 1024, 0, stream>>>(
      xyz, points, W1, W2, W3, center, ddws, xsb, ysb, zsb, ppsb,
      Wbf, pointsbf, kidx, b1, Y1, psumA);
  // P4: fps g[448,512) + knn[384,448) + gemm1 tau[128,192)
  fps_phase<4><<<BB + 128 + 256, 1024, 0, stream>>>(
      xyz, points, W1, W2, W3, center, ddws, xsb, ysb, zsb, ppsb,
      Wbf, pointsbf, kidx, b1, Y1, psumA);

  // tail: knn[448,512) (2-wave) overlapped with gemm1 tau[192,224)
  knn_gemm_tail<<<1024, 256, 0, stream>>>(
      xsb, ysb, zsb, ppsb, center, kidx, Wbf, b1, pointsbf, Y1, psumA);
  // gemm1e: tau[224,256)
  gemm1e_kernel<<<512, 256, 0, stream>>>(Wbf, b1, pointsbf, kidx, Y1, psumA);

  gemm_kernel<128, 1, true, true, false><<<4096, 256, 0, stream>>>(
      Wbf + 16384, b2, Y1, psumA, g1, be1, Y2, psumB, nullptr, nullptr);

  gemm_kernel<256, 1, true, false, true><<<4096, 256, 0, stream>>>(
      Wbf + 32768, b3, Y2, psumB, g2, be2, nullptr, psumC, rawmax, rawmin);

  finish3_kernel<<<512, 256, 0, stream>>>(psumC, g3, be3, rawmax, rawmin, opool);
}

// Round 18
// 707.725 us; speedup vs baseline: 1.0644x; 1.0167x over previous
//
#include <hip/hip_runtime.h>
#include <hip/hip_bf16.h>

#define BB 16
#define NN 8192
#define GG 512
#define KK 32
#define DD 128

typedef __attribute__((ext_vector_type(8))) short bf16x8;
typedef __attribute__((ext_vector_type(4))) float f32x4;
typedef __attribute__((ext_vector_type(2))) float f32x2;
typedef __attribute__((ext_vector_type(2))) unsigned int u32x2;
typedef __attribute__((ext_vector_type(4))) unsigned int u32x4;
typedef __attribute__((ext_vector_type(2))) unsigned long long u64x2;

__device__ __forceinline__ unsigned short f2bf(float f){
  unsigned int u = __builtin_bit_cast(unsigned int, f);
  unsigned int r = (u + 0x7FFFu + ((u >> 16) & 1u)) >> 16;
  return (unsigned short)r;
}
__device__ __forceinline__ float bf2f(unsigned short h){
  unsigned int u = ((unsigned int)h) << 16;
  return __builtin_bit_cast(float, u);
}

// DPP wave64 reductions: row_shr 1/2/4/8 then row_bcast15/31; result in lane 63.
__device__ __forceinline__ float wave_max_f32(float v){
  int x = __builtin_bit_cast(int, v);
#define STEPMAX(C) { int y = __builtin_amdgcn_update_dpp(x, x, C, 0xF, 0xF, false); \
  float f = fmaxf(__builtin_bit_cast(float,x), __builtin_bit_cast(float,y)); x = __builtin_bit_cast(int,f); }
  STEPMAX(0x111) STEPMAX(0x112) STEPMAX(0x114) STEPMAX(0x118) STEPMAX(0x142) STEPMAX(0x143)
#undef STEPMAX
  return __builtin_bit_cast(float, __builtin_amdgcn_readlane(x, 63));
}
__device__ __forceinline__ float wave_min_f32(float v){
  int x = __builtin_bit_cast(int, v);
#define STEPMIN(C) { int y = __builtin_amdgcn_update_dpp(x, x, C, 0xF, 0xF, false); \
  float f = fminf(__builtin_bit_cast(float,x), __builtin_bit_cast(float,y)); x = __builtin_bit_cast(int,f); }
  STEPMIN(0x111) STEPMIN(0x112) STEPMIN(0x114) STEPMIN(0x118) STEPMIN(0x142) STEPMIN(0x143)
#undef STEPMIN
  return __builtin_bit_cast(float, __builtin_amdgcn_readlane(x, 63));
}
__device__ __forceinline__ int wave_min_i32(int v){
  int x = v;
#define STEPMNI(C) { int y = __builtin_amdgcn_update_dpp(x, x, C, 0xF, 0xF, false); \
  x = (y < x) ? y : x; }
  STEPMNI(0x111) STEPMNI(0x112) STEPMNI(0x114) STEPMNI(0x118) STEPMNI(0x142) STEPMNI(0x143)
#undef STEPMNI
  return __builtin_amdgcn_readlane(x, 63);
}

// ---------------- KNN 2-wave group worker (frozen R13) ----------------------
__device__ __forceinline__ void knn_group(int bg, int t128,
    const float* __restrict__ xs, const float* __restrict__ ys,
    const float* __restrict__ zs, const float* __restrict__ pps,
    const float* __restrict__ center, int* __restrict__ kidx,
    unsigned long long (*wlist)[KK], int* outidx)
{
#pragma clang fp contract(off)
  int lane = t128 & 63, w = t128 >> 6;
  int b = bg >> 9;
  const float cx = center[(size_t)bg*3+0];
  const float cy = center[(size_t)bg*3+1];
  const float cz = center[(size_t)bg*3+2];
  const float ccv = (cx*cx + cy*cy) + cz*cz;   // same expr tree as ref cc
  const float* xb = xs  + (size_t)b*NN;
  const float* yb = ys  + (size_t)b*NN;
  const float* zb = zs  + (size_t)b*NN;
  const float* pb = pps + (size_t)b*NN;

  f32x2 d2v[32];
  float gmin[8]; int gidx[8];
#pragma unroll
  for (int gi = 0; gi < 8; ++gi){ gmin[gi] = 3.4e38f; gidx[gi] = 0x7FFFFFFF; }
  int nb = w*128 + 2*lane;
  f32x2 cxv = (f32x2){cx, cx}, cyv = (f32x2){cy, cy}, czv = (f32x2){cz, cz};
  f32x2 ccvv = (f32x2){ccv, ccv};
#pragma unroll
  for (int q = 0; q < 32; ++q){
    int n0 = q*256 + nb;
    f32x2 x = *(const f32x2*)(xb + n0);
    f32x2 y = *(const f32x2*)(yb + n0);
    f32x2 z = *(const f32x2*)(zb + n0);
    f32x2 pp = *(const f32x2*)(pb + n0);
    f32x2 dot = (cxv*x + cyv*y) + czv*z;
    f32x2 d = (ccvv + pp) - 2.0f*dot;
    d2v[q] = d;
    int gi = q >> 2;
    if (d.x < gmin[gi]){ gmin[gi] = d.x; gidx[gi] = n0; }
    if (d.y < gmin[gi]){ gmin[gi] = d.y; gidx[gi] = n0 + 1; }
  }
  float bv = gmin[0]; int bi = gidx[0];
#pragma unroll
  for (int gi = 1; gi < 8; ++gi)
    if (gmin[gi] < bv){ bv = gmin[gi]; bi = gidx[gi]; }

  unsigned long long mykey = ~0ULL;
  for (int k = 0; k < KK; ++k){
    float wmin = wave_min_f32(bv);
    unsigned long long mask = __ballot(bv == wmin);
    int n_win;
    if (__popcll(mask) == 1){
      n_win = __builtin_amdgcn_readlane(bi, (int)__builtin_ctzll(mask));
    } else {
      int cand = (bv == wmin) ? bi : 0x7FFFFFFF;
      n_win = wave_min_i32(cand);
    }
    if (lane == k){
      unsigned int fm = __builtin_bit_cast(unsigned int, wmin);
      unsigned int mapd = fm ^ (unsigned int)(((int)fm >> 31) | 0x80000000);
      mykey = ((unsigned long long)mapd << 32) | (unsigned int)n_win;
    }
    if (bi == n_win){                     // owner lane only
#define RESCAN2(GI) { \
      float nm = 3.4e38f; int ni = 0x7FFFFFFF; \
      _Pragma("unroll") \
      for (int j = 0; j < 4; ++j){ \
        int q = GI*4 + j; \
        int n0 = q*256 + nb; \
        f32x2 v = d2v[q]; \
        if (n0 == n_win) v.x = 3.4e38f; \
        if (n0 + 1 == n_win) v.y = 3.4e38f; \
        d2v[q] = v; \
        if (v.x < nm){ nm = v.x; ni = n0; } \
        if (v.y < nm){ nm = v.y; ni = n0 + 1; } } \
      gmin[GI] = nm; gidx[GI] = ni; }
      switch (n_win >> 10){
        case 0: RESCAN2(0); break;
        case 1: RESCAN2(1); break;
        case 2: RESCAN2(2); break;
        case 3: RESCAN2(3); break;
        case 4: RESCAN2(4); break;
        case 5: RESCAN2(5); break;
        case 6: RESCAN2(6); break;
        default: RESCAN2(7); break;
      }
#undef RESCAN2
      bv = gmin[0]; bi = gidx[0];
#pragma unroll
      for (int gi = 1; gi < 8; ++gi)
        if (gmin[gi] < bv){ bv = gmin[gi]; bi = gidx[gi]; }
    }
  }

  if (lane < KK) wlist[w][lane] = mykey;
  __syncthreads();
  if (lane < KK){
    unsigned long long K = mykey;
    const unsigned long long* other = wlist[1 - w];
    int cnt = 0;
#pragma unroll
    for (int j = 0; j < KK; ++j) cnt += (other[j] < K) ? 1 : 0;
    int rank = lane + cnt;
    if (rank < KK) outidx[rank] = (int)(unsigned int)K;
  }
  __syncthreads();
  if (t128 < KK) kidx[(size_t)bg*KK + t128] = outidx[t128];
}

// ---------------- FPS slice (frozen R15) ------------------------------------
__device__ __forceinline__ void fps_part(const float* __restrict__ xyz,
    float* __restrict__ center_out, float* __restrict__ ddws,
    int b, int t, int g0, int g1, bool save_dd, char* lds)
{
#pragma clang fp contract(off)
  float (*tbl)[4]    = (float(*)[4])lds;                       // 128 KB
  float (*outbuf)[4] = (float(*)[4])(lds + 131072);            // 2 KB
  unsigned long long (*slot)[2] =
      (unsigned long long(*)[2])(lds + 131072 + 2048);         // 48 B
  int lane = t & 63, wid = t >> 6;
  const float* base = xyz + (size_t)b * NN * 3;
  f32x2 px[4], py[4], pz[4], dd[4];
  if (g0 == 1){
#pragma unroll
    for (int i = 0; i < 4; ++i) dd[i] = (f32x2){1e10f, 1e10f};
  } else {
    const float* dp = ddws + ((size_t)b*1024 + t)*8;
    f32x4 s0 = *(const f32x4*)dp;
    f32x4 s1 = *(const f32x4*)(dp + 4);
    dd[0] = (f32x2){s0[0], s0[1]};
    dd[1] = (f32x2){s0[2], s0[3]};
    dd[2] = (f32x2){s1[0], s1[1]};
    dd[3] = (f32x2){s1[2], s1[3]};
  }
#pragma unroll
  for (int i = 0; i < 4; ++i){
    int n0 = i*2048 + t, n1 = n0 + 1024;
    float x0 = base[n0*3+0], y0 = base[n0*3+1], z0 = base[n0*3+2];
    float x1 = base[n1*3+0], y1 = base[n1*3+1], z1 = base[n1*3+2];
    px[i] = (f32x2){x0, x1}; py[i] = (f32x2){y0, y1}; pz[i] = (f32x2){z0, z1};
    f32x4 c0 = {x0, y0, z0, 0.f}, c1 = {x1, y1, z1, 0.f};
    *(f32x4*)&tbl[n0][0] = c0;
    *(f32x4*)&tbl[n1][0] = c1;
  }
  float lx, ly, lz;
  if (g0 == 1){ lx = base[0]; ly = base[1]; lz = base[2]; }
  else {
    lx = center_out[((size_t)b*GG + g0 - 1)*3 + 0];
    ly = center_out[((size_t)b*GG + g0 - 1)*3 + 1];
    lz = center_out[((size_t)b*GG + g0 - 1)*3 + 2];
  }
  if (t < 6) slot[t >> 1][t & 1] = 0;
  __syncthreads();
  for (int g = g0; g < g1; ++g){
    f32x2 lxv = (f32x2){lx, lx}, lyv = (f32x2){ly, ly}, lzv = (f32x2){lz, lz};
    f32x2 vm = (f32x2){-1.f, -1.f};
#pragma unroll
    for (int i = 0; i < 4; ++i){
      f32x2 dx = px[i] - lxv, dy = py[i] - lyv, dz = pz[i] - lzv;
      f32x2 s = (dx*dx + dy*dy) + dz*dz;
      f32x2 nd = __builtin_elementwise_min(dd[i], s);
      dd[i] = nd;
      vm = __builtin_elementwise_max(vm, nd);
    }
    float m = fmaxf(vm.x, vm.y);
    int mi = 0x7FFFFFFF;
#pragma unroll
    for (int i = 3; i >= 0; --i){
      int n0 = i*2048 + t;
      if (dd[i].y == m) mi = n0 + 1024;
      if (dd[i].x == m) mi = n0;
    }
    float wmax = wave_max_f32(m);
    bool cnd = (m == wmax);
    unsigned long long mask = __ballot(cnd);
    int n_wave;
    if (__popcll(mask) == 1){
      n_wave = __builtin_amdgcn_readlane(mi, (int)__builtin_ctzll(mask));
    } else {
      int cand = cnd ? mi : 0x7FFFFFFF;
      n_wave = wave_min_i32(cand);
    }
    unsigned long long key =
        ((unsigned long long)__builtin_bit_cast(unsigned int, wmax) << 32)
      | (unsigned int)(~n_wave);
    int p = g - (g/3)*3;                             // g % 3
    if (lane == 0) atomicMax(&slot[p][wid & 1], key);
    __syncthreads();
    u64x2 sA = *(const u64x2*)&slot[p][0];
    unsigned long long M = sA.x > sA.y ? sA.x : sA.y;
    int n_win = (int)~((unsigned int)M);
    f32x4 cw = *(const f32x4*)&tbl[n_win][0];
    lx = cw[0]; ly = cw[1]; lz = cw[2];
    if (t == 0) *(f32x4*)&outbuf[g - g0][0] = cw;
    if (t < 2){
      int z = p + 2; if (z >= 3) z -= 3;             // (g+2) % 3
      slot[z][t] = 0;
    }
  }
  __syncthreads();
  if (t < g1 - g0){
    int g = g0 + t;
    center_out[((size_t)b*GG + g)*3 + 0] = outbuf[t][0];
    center_out[((size_t)b*GG + g)*3 + 1] = outbuf[t][1];
    center_out[((size_t)b*GG + g)*3 + 2] = outbuf[t][2];
  }
  if (g0 == 1 && t == 0){
    center_out[((size_t)b*GG)*3 + 0] = base[0];
    center_out[((size_t)b*GG)*3 + 1] = base[1];
    center_out[((size_t)b*GG)*3 + 2] = base[2];
  }
  if (save_dd){
    f32x4 s0 = {dd[0].x, dd[0].y, dd[1].x, dd[1].y};
    f32x4 s1 = {dd[2].x, dd[2].y, dd[3].x, dd[3].y};
    float* dp = ddws + ((size_t)b*1024 + t)*8;
    *(f32x4*)dp       = s0;
    *(f32x4*)(dp + 4) = s1;
  }
}

// ---------------- GEMM body (frozen R14; MODE0 only used now) ---------------
template<int OC, int MODE, bool STATS, bool STORE, bool POOL>
__device__ __forceinline__ void gemm_body(int sbid, int t,
    const unsigned short* __restrict__ Wbf, const float* __restrict__ bias,
    const unsigned short* __restrict__ pointsbf, const int* __restrict__ kidx,
    const unsigned short* __restrict__ Xin,
    const float* __restrict__ psum_in, const float* __restrict__ gin,
    const float* __restrict__ bein,
    unsigned short* __restrict__ Yout, float* __restrict__ psum,
    float* __restrict__ rawmax, float* __restrict__ rawmin,
    unsigned short* smem, float* ssc, float* ssh)
{
  constexpr int MF = OC / 64;
  int l = t & 63, w = t >> 6;
  int l15 = l & 15, lh = l >> 4;
  int jbase = sbid * 64;
  int obase = w * (OC / 4);
  int slot = sbid & 63;

  if constexpr (MODE == 1){
    if (t < 128){
      float s = 0.f, q = 0.f;
#pragma unroll
      for (int sl = 0; sl < 64; ++sl){
        s += psum_in[sl*128 + t];
        q += psum_in[64*128 + sl*128 + t];
      }
      const float inv = 1.f / 262144.f;    // B*K*G
      float mean = s * inv;
      float var  = q * inv - mean*mean;
      float sc = gin[t] * rsqrtf(var + 1e-5f);
      ssc[t] = sc;
      ssh[t] = bein[t] - mean*sc;
    }
  }

  bf16x8 a[MF][4];
#pragma unroll
  for (int m = 0; m < MF; ++m)
#pragma unroll
    for (int kf = 0; kf < 4; ++kf){
      int row = obase + m*16 + l15;
      int c8  = kf*32 + lh*8;
      a[m][kf] = *(const bf16x8*)(Wbf + (size_t)row*128 + c8);
    }

  if constexpr (MODE == 1) __syncthreads();

#pragma unroll
  for (int q = 0; q < 4; ++q){
    int ci = q*256 + t;
    int j = ci >> 4, cc = ci & 15;
    unsigned short* dst = &smem[j*128 + ((cc ^ (j & 15)) * 8)];
    if constexpr (MODE == 0){
      int jg = jbase + j;
      int bb = jg >> 14;
      int row = kidx[jg];
      const unsigned short* src = pointsbf + ((size_t)bb*NN + row)*DD + cc*8;
      *(u32x4*)dst = *(const u32x4*)src;
    } else {
      const unsigned short* src = Xin + ((size_t)(jbase + j))*128 + cc*8;
      u32x4 v = *(const u32x4*)src;
      int c0 = cc * 8;
      unsigned int wo[4];
#pragma unroll
      for (int p = 0; p < 4; ++p){
        float x0 = bf2f((unsigned short)(v[p] & 0xFFFFu));
        float x1 = bf2f((unsigned short)(v[p] >> 16));
        x0 = fmaxf(fmaf(x0, ssc[c0 + 2*p],     ssh[c0 + 2*p]),     0.f);
        x1 = fmaxf(fmaf(x1, ssc[c0 + 2*p + 1], ssh[c0 + 2*p + 1]), 0.f);
        wo[p] = f2bf(x0) | ((unsigned int)f2bf(x1) << 16);
      }
      u32x4 pv = {wo[0], wo[1], wo[2], wo[3]};
      *(u32x4*)dst = pv;
    }
  }
  __syncthreads();

  f32x4 acc[MF][4];
#pragma unroll
  for (int m = 0; m < MF; ++m)
#pragma unroll
    for (int n = 0; n < 4; ++n)
      acc[m][n] = (f32x4){0.f, 0.f, 0.f, 0.f};

#pragma unroll
  for (int n = 0; n < 4; ++n){
    bf16x8 bfr[4];
    int j = n*16 + l15;
#pragma unroll
    for (int kf = 0; kf < 4; ++kf){
      int ch = kf*4 + lh;
      bfr[kf] = *(const bf16x8*)&smem[j*128 + ((ch ^ (j & 15)) * 8)];
    }
#pragma unroll
    for (int m = 0; m < MF; ++m)
#pragma unroll
      for (int kf = 0; kf < 4; ++kf)
        acc[m][n] = __builtin_amdgcn_mfma_f32_16x16x32_bf16(a[m][kf], bfr[kf], acc[m][n], 0, 0, 0);
  }

#pragma unroll
  for (int m = 0; m < MF; ++m){
    int o0 = obase + m*16 + lh*4;
    f32x4 bv = *(const f32x4*)(bias + o0);
#pragma unroll
    for (int n = 0; n < 4; ++n) acc[m][n] += bv;
  }

  if constexpr (STATS){
#pragma unroll
    for (int m = 0; m < MF; ++m){
#pragma unroll
      for (int r = 0; r < 4; ++r){
        float s = 0.f, q2 = 0.f;
#pragma unroll
        for (int n = 0; n < 4; ++n){ float v = acc[m][n][r]; s += v; q2 += v*v; }
        s  += __shfl_xor(s, 1);  s  += __shfl_xor(s, 2);  s  += __shfl_xor(s, 4);  s  += __shfl_xor(s, 8);
        q2 += __shfl_xor(q2, 1); q2 += __shfl_xor(q2, 2); q2 += __shfl_xor(q2, 4); q2 += __shfl_xor(q2, 8);
        if (l15 == 0){
          int o = obase + m*16 + lh*4 + r;
          atomicAdd(psum + slot*OC + o, s);
          atomicAdd(psum + 64*OC + slot*OC + o, q2);
        }
      }
    }
  }

  if constexpr (POOL){
#pragma unroll
    for (int m = 0; m < MF; ++m){
      int o0 = obase + m*16 + lh*4;
      f32x4 gmx0, gmx1, gmn0, gmn1;
#pragma unroll
      for (int r = 0; r < 4; ++r){
        float v0 = acc[m][0][r], v1 = acc[m][1][r];
        float v2 = acc[m][2][r], v3 = acc[m][3][r];
        float ax0 = fmaxf(v0, v1), ax1 = fmaxf(v2, v3);
        float an0 = fminf(v0, v1), an1 = fminf(v2, v3);
#pragma unroll
        for (int mk = 1; mk < 16; mk <<= 1){
          ax0 = fmaxf(ax0, __shfl_xor(ax0, mk));
          ax1 = fmaxf(ax1, __shfl_xor(ax1, mk));
          an0 = fminf(an0, __shfl_xor(an0, mk));
          an1 = fminf(an1, __shfl_xor(an1, mk));
        }
        gmx0[r] = ax0; gmx1[r] = ax1; gmn0[r] = an0; gmn1[r] = an1;
      }
      if (l15 == 0){
        int gg = jbase >> 5;
        *(f32x4*)(rawmax + (size_t)gg*256 + o0)       = gmx0;
        *(f32x4*)(rawmax + (size_t)(gg + 1)*256 + o0) = gmx1;
        *(f32x4*)(rawmin + (size_t)gg*256 + o0)       = gmn0;
        *(f32x4*)(rawmin + (size_t)(gg + 1)*256 + o0) = gmn1;
      }
    }
  }

  if constexpr (STORE){
    __syncthreads();
#pragma unroll
    for (int m = 0; m < MF; ++m){
      int o0 = obase + m*16 + lh*4;
      int co = o0 >> 2;
#pragma unroll
      for (int n = 0; n < 4; ++n){
        int j = n*16 + l15;
        unsigned int w0 = f2bf(acc[m][n][0]) | ((unsigned int)f2bf(acc[m][n][1]) << 16);
        unsigned int w1 = f2bf(acc[m][n][2]) | ((unsigned int)f2bf(acc[m][n][3]) << 16);
        u32x2 pv = {w0, w1};
        *(u32x2*)&smem[j*OC + ((co ^ ((j & 15) << 1)) * 4)] = pv;
      }
    }
    __syncthreads();
    constexpr int CPR = OC / 4;
    constexpr int CPT = (64 * CPR) / 256;
#pragma unroll
    for (int q = 0; q < CPT; ++q){
      int ci = q*256 + t;
      int j = ci / CPR, co = ci % CPR;
      u32x2 v = *(const u32x2*)&smem[j*OC + ((co ^ ((j & 15) << 1)) * 4)];
      *(u32x2*)(Yout + (size_t)(jbase + j)*OC + co*4) = v;
    }
  }
}

// ---------------- gemm2/3: two j-tiles per block, hoisted bnprep + A --------
template<int OC, bool STORE, bool POOL>
__global__ __launch_bounds__(256)
void gemm23_kernel(const unsigned short* __restrict__ Wbf, const float* __restrict__ bias,
                   const unsigned short* __restrict__ Xin,
                   const float* __restrict__ psum_in, const float* __restrict__ gin,
                   const float* __restrict__ bein,
                   unsigned short* __restrict__ Yout, float* __restrict__ psum,
                   float* __restrict__ rawmax, float* __restrict__ rawmin)
{
  constexpr int MF = OC / 64;
  __shared__ unsigned short smem[64 * OC];
  __shared__ float ssc[128], ssh[128];
  int bid = blockIdx.x, t = threadIdx.x;
  int l = t & 63, w = t >> 6;
  int l15 = l & 15, lh = l >> 4;
  int obase = w * (OC / 4);

  // bnprep once (identical add order -> bit-exact)
  if (t < 128){
    float s = 0.f, q = 0.f;
#pragma unroll
    for (int sl = 0; sl < 64; ++sl){
      s += psum_in[sl*128 + t];
      q += psum_in[64*128 + sl*128 + t];
    }
    const float inv = 1.f / 262144.f;
    float mean = s * inv;
    float var  = q * inv - mean*mean;
    float sc = gin[t] * rsqrtf(var + 1e-5f);
    ssc[t] = sc;
    ssh[t] = bein[t] - mean*sc;
  }

  // A fragments once (W shared by both tiles)
  bf16x8 a[MF][4];
#pragma unroll
  for (int m = 0; m < MF; ++m)
#pragma unroll
    for (int kf = 0; kf < 4; ++kf){
      int row = obase + m*16 + l15;
      int c8  = kf*32 + lh*8;
      a[m][kf] = *(const bf16x8*)(Wbf + (size_t)row*128 + c8);
    }
  __syncthreads();

  for (int half = 0; half < 2; ++half){
    int u = bid + half*2048;                // [0,4096) bijective over both halves
    int sbid = (u & 7) * 512 + (u >> 3);
    int jbase = sbid * 64;
    int slot = sbid & 63;

    // stage X = relu(sc*Y+sh) -> bf16, swizzled
#pragma unroll
    for (int q = 0; q < 4; ++q){
      int ci = q*256 + t;
      int j = ci >> 4, cc = ci & 15;
      unsigned short* dst = &smem[j*128 + ((cc ^ (j & 15)) * 8)];
      const unsigned short* src = Xin + ((size_t)(jbase + j))*128 + cc*8;
      u32x4 v = *(const u32x4*)src;
      int c0 = cc * 8;
      unsigned int wo[4];
#pragma unroll
      for (int p = 0; p < 4; ++p){
        float x0 = bf2f((unsigned short)(v[p] & 0xFFFFu));
        float x1 = bf2f((unsigned short)(v[p] >> 16));
        x0 = fmaxf(fmaf(x0, ssc[c0 + 2*p],     ssh[c0 + 2*p]),     0.f);
        x1 = fmaxf(fmaf(x1, ssc[c0 + 2*p + 1], ssh[c0 + 2*p + 1]), 0.f);
        wo[p] = f2bf(x0) | ((unsigned int)f2bf(x1) << 16);
      }
      u32x4 pv = {wo[0], wo[1], wo[2], wo[3]};
      *(u32x4*)dst = pv;
    }
    __syncthreads();

    f32x4 acc[MF][4];
#pragma unroll
    for (int m = 0; m < MF; ++m)
#pragma unroll
      for (int n = 0; n < 4; ++n)
        acc[m][n] = (f32x4){0.f, 0.f, 0.f, 0.f};

#pragma unroll
    for (int n = 0; n < 4; ++n){
      bf16x8 bfr[4];
      int j = n*16 + l15;
#pragma unroll
      for (int kf = 0; kf < 4; ++kf){
        int ch = kf*4 + lh;
        bfr[kf] = *(const bf16x8*)&smem[j*128 + ((ch ^ (j & 15)) * 8)];
      }
#pragma unroll
      for (int m = 0; m < MF; ++m)
#pragma unroll
        for (int kf = 0; kf < 4; ++kf)
          acc[m][n] = __builtin_amdgcn_mfma_f32_16x16x32_bf16(a[m][kf], bfr[kf], acc[m][n], 0, 0, 0);
    }

#pragma unroll
    for (int m = 0; m < MF; ++m){
      int o0 = obase + m*16 + lh*4;
      f32x4 bv = *(const f32x4*)(bias + o0);
#pragma unroll
      for (int n = 0; n < 4; ++n) acc[m][n] += bv;
    }

    // stats (same per-tile slot mapping as before)
#pragma unroll
    for (int m = 0; m < MF; ++m){
#pragma unroll
      for (int r = 0; r < 4; ++r){
        float s = 0.f, q2 = 0.f;
#pragma unroll
        for (int n = 0; n < 4; ++n){ float v = acc[m][n][r]; s += v; q2 += v*v; }
        s  += __shfl_xor(s, 1);  s  += __shfl_xor(s, 2);  s  += __shfl_xor(s, 4);  s  += __shfl_xor(s, 8);
        q2 += __shfl_xor(q2, 1); q2 += __shfl_xor(q2, 2); q2 += __shfl_xor(q2, 4); q2 += __shfl_xor(q2, 8);
        if (l15 == 0){
          int o = obase + m*16 + lh*4 + r;
          atomicAdd(psum + slot*OC + o, s);
          atomicAdd(psum + 64*OC + slot*OC + o, q2);
        }
      }
    }

    if constexpr (POOL){
#pragma unroll
      for (int m = 0; m < MF; ++m){
        int o0 = obase + m*16 + lh*4;
        f32x4 gmx0, gmx1, gmn0, gmn1;
#pragma unroll
        for (int r = 0; r < 4; ++r){
          float v0 = acc[m][0][r], v1 = acc[m][1][r];
          float v2 = acc[m][2][r], v3 = acc[m][3][r];
          float ax0 = fmaxf(v0, v1), ax1 = fmaxf(v2, v3);
          float an0 = fminf(v0, v1), an1 = fminf(v2, v3);
#pragma unroll
          for (int mk = 1; mk < 16; mk <<= 1){
            ax0 = fmaxf(ax0, __shfl_xor(ax0, mk));
            ax1 = fmaxf(ax1, __shfl_xor(ax1, mk));
            an0 = fminf(an0, __shfl_xor(an0, mk));
            an1 = fminf(an1, __shfl_xor(an1, mk));
          }
          gmx0[r] = ax0; gmx1[r] = ax1; gmn0[r] = an0; gmn1[r] = an1;
        }
        if (l15 == 0){
          int gg = jbase >> 5;
          *(f32x4*)(rawmax + (size_t)gg*256 + o0)       = gmx0;
          *(f32x4*)(rawmax + (size_t)(gg + 1)*256 + o0) = gmx1;
          *(f32x4*)(rawmin + (size_t)gg*256 + o0)       = gmn0;
          *(f32x4*)(rawmin + (size_t)(gg + 1)*256 + o0) = gmn1;
        }
      }
    }

    if constexpr (STORE){
      __syncthreads();
#pragma unroll
      for (int m = 0; m < MF; ++m){
        int o0 = obase + m*16 + lh*4;
        int co = o0 >> 2;
#pragma unroll
        for (int n = 0; n < 4; ++n){
          int j = n*16 + l15;
          unsigned int w0 = f2bf(acc[m][n][0]) | ((unsigned int)f2bf(acc[m][n][1]) << 16);
          unsigned int w1 = f2bf(acc[m][n][2]) | ((unsigned int)f2bf(acc[m][n][3]) << 16);
          u32x2 pv = {w0, w1};
          *(u32x2*)&smem[j*OC + ((co ^ ((j & 15) << 1)) * 4)] = pv;
        }
      }
      __syncthreads();
      constexpr int CPR = OC / 4;
      constexpr int CPT = (64 * CPR) / 256;
#pragma unroll
      for (int q = 0; q < CPT; ++q){
        int ci = q*256 + t;
        int j = ci / CPR, co = ci % CPR;
        u32x2 v = *(const u32x2*)&smem[j*OC + ((co ^ ((j & 15) << 1)) * 4)];
        *(u32x2*)(Yout + (size_t)(jbase + j)*OC + co*4) = v;
      }
    }
    __syncthreads();    // smem safe before next half's staging
  }
}

// ---------------- 5-phase fps pipeline (frozen R17) -------------------------
#define LDSB (131072 + 2048 + 64)

template<int PH>
__global__ __launch_bounds__(1024)
void fps_phase(const float* __restrict__ xyz, const float* __restrict__ points,
               const float* __restrict__ W1, const float* __restrict__ W2,
               const float* __restrict__ W3,
               float* __restrict__ center_out, float* __restrict__ ddws,
               float* __restrict__ xs, float* __restrict__ ys,
               float* __restrict__ zs, float* __restrict__ pps,
               unsigned short* __restrict__ Wbf,
               unsigned short* __restrict__ pointsbf,
               int* __restrict__ kidx,
               const float* __restrict__ b1,
               unsigned short* __restrict__ Y1, float* __restrict__ psumA)
{
  __shared__ __attribute__((aligned(16))) char lds[LDSB];
  int t = threadIdx.x;
  if (blockIdx.x < BB){
    constexpr int g0 = (PH == 0) ? 1 : (PH == 1 ? 128 : (PH == 2 ? 256 : (PH == 3 ? 384 : 448)));
    constexpr int g1 = (PH == 0) ? 128 : (PH == 1 ? 256 : (PH == 2 ? 384 : (PH == 3 ? 448 : 512)));
    fps_part(xyz, center_out, ddws, blockIdx.x, t, g0, g1, PH < 4, lds);
    return;
  }
  if constexpr (PH == 0){
#pragma clang fp contract(off)
    int pb = blockIdx.x - BB;
    size_t i = ((size_t)pb*1024 + t)*8;
    f32x4 u0 = *(const f32x4*)(points + i);
    f32x4 u1 = *(const f32x4*)(points + i + 4);
    unsigned int w0 = f2bf(u0[0]) | ((unsigned int)f2bf(u0[1]) << 16);
    unsigned int w1 = f2bf(u0[2]) | ((unsigned int)f2bf(u0[3]) << 16);
    unsigned int w2 = f2bf(u1[0]) | ((unsigned int)f2bf(u1[1]) << 16);
    unsigned int w3 = f2bf(u1[2]) | ((unsigned int)f2bf(u1[3]) << 16);
    u32x4 pv = {w0, w1, w2, w3};
    *(u32x4*)(pointsbf + i) = pv;
    if (pb < 128){
      int n = pb*1024 + t;
      float x = xyz[(size_t)n*3 + 0];
      float y = xyz[(size_t)n*3 + 1];
      float z = xyz[(size_t)n*3 + 2];
      xs[n] = x; ys[n] = y; zs[n] = z;
      pps[n] = (x*x + y*y) + z*z;
    }
    if (pb < 64){
      int n = pb*1024 + t;
      float v;
      if (n < 16384)      v = W1[n];
      else if (n < 32768) v = W2[n - 16384];
      else                v = W3[n - 32768];
      Wbf[n] = f2bf(v);
    }
  } else {
    int pb = blockIdx.x - BB;
    constexpr int KNB  = (PH == 4) ? 128 : 256;
    constexpr int KNG0 = (PH - 1) * 128;
    if (pb < KNB){
      unsigned long long (*kwl)[2][KK] = (unsigned long long(*)[2][KK])lds;
      int* kout = (int*)(lds + 8*2*KK*8);
      int sub = t >> 7, t128 = t & 127;
      int idx = pb*8 + sub;
      int b, g;
      if constexpr (PH == 4){ b = idx >> 6; g = 384 + (idx & 63); }
      else                  { b = idx >> 7; g = KNG0 + (idx & 127); }
      knn_group(b*GG + g, t128, xs, ys, zs, pps, center_out, kidx,
                &kwl[sub][0], kout + sub*KK);
    } else if constexpr (PH >= 2){
      constexpr int TAU0 = (PH - 2) * 64;
      int hb = pb - KNB;
      int sub = t >> 8, t256 = t & 255;
      int u = hb*4 + sub;
      int us = (u & 7) * 128 + (u >> 3);
      int b = us >> 6, tau = TAU0 + (us & 63);
      unsigned short* smem = (unsigned short*)(lds + sub*16384);
      gemm_body<128, 0, true, true, false>(b*256 + tau, t256,
          Wbf, b1, pointsbf, kidx, nullptr, nullptr, nullptr, nullptr,
          Y1, psumA, nullptr, nullptr, smem, nullptr, nullptr);
    }
  }
}

// ---------------- tail: knn[448,512) 2-wave [bid<512] + gemm1 tau[192,224) --
__global__ __launch_bounds__(256)
void knn_gemm_tail(const float* __restrict__ xs, const float* __restrict__ ys,
                   const float* __restrict__ zs, const float* __restrict__ pps,
                   const float* __restrict__ center, int* __restrict__ kidx,
                   const unsigned short* __restrict__ Wbf,
                   const float* __restrict__ b1,
                   const unsigned short* __restrict__ pointsbf,
                   unsigned short* __restrict__ Y1, float* __restrict__ psumA)
{
  __shared__ unsigned short smem[64 * 128];
  __shared__ unsigned long long kwl[2][2][KK] __attribute__((aligned(16)));
  __shared__ int kout[2][KK];
  int bid = blockIdx.x, t = threadIdx.x;
  if (bid < 512){
    int swz = (bid & 7) * 64 + (bid >> 3);
    int sub = t >> 7, t128 = t & 127;
    int idx = swz*2 + sub;
    int b = idx >> 6, g = 448 + (idx & 63);
    knn_group(b*GG + g, t128, xs, ys, zs, pps, center, kidx,
              kwl[sub], kout[sub]);
    return;
  }
  int h = bid - 512;
  int hs = (h & 7) * 64 + (h >> 3);
  int b = hs >> 5, tau = 192 + (hs & 31);
  gemm_body<128, 0, true, true, false>(b*256 + tau, t,
      Wbf, b1, pointsbf, kidx, nullptr, nullptr, nullptr, nullptr,
      Y1, psumA, nullptr, nullptr, smem, nullptr, nullptr);
}

// ---------------- gemm1e: tiles tau in [224,256) ----------------------------
__global__ __launch_bounds__(256)
void gemm1e_kernel(const unsigned short* __restrict__ Wbf, const float* __restrict__ b1,
                   const unsigned short* __restrict__ pointsbf,
                   const int* __restrict__ kidx,
                   unsigned short* __restrict__ Y1, float* __restrict__ psumA)
{
  __shared__ unsigned short smem[64 * 128];
  int bid = blockIdx.x, t = threadIdx.x;
  int hs = (bid & 7) * 64 + (bid >> 3);
  int b = hs >> 5, tau = 224 + (hs & 31);
  gemm_body<128, 0, true, true, false>(b*256 + tau, t,
      Wbf, b1, pointsbf, kidx, nullptr, nullptr, nullptr, nullptr,
      Y1, psumA, nullptr, nullptr, smem, nullptr, nullptr);
}

// ---------------- finish layer 3 --------------------------------------------
__global__ __launch_bounds__(256)
void finish3_kernel(const float* __restrict__ psumC, const float* __restrict__ g3,
                    const float* __restrict__ be3, const float* __restrict__ rawmax,
                    const float* __restrict__ rawmin, float* __restrict__ opool)
{
  __shared__ float ssc[256], ssh[256];
  int t = threadIdx.x;
  {
    float s = 0.f, q = 0.f;
#pragma unroll
    for (int sl = 0; sl < 64; ++sl){
      s += psumC[sl*256 + t];
      q += psumC[64*256 + sl*256 + t];
    }
    const float inv = 1.f / 262144.f;
    float mean = s * inv;
    float var  = q * inv - mean*mean;
    float sc = g3[t] * rsqrtf(var + 1e-5f);
    ssc[t] = sc;
    ssh[t] = be3[t] - mean*sc;
  }
  __syncthreads();
  float sc = ssc[t], sh = ssh[t];
  int gg0 = blockIdx.x * 16;
#pragma unroll
  for (int i = 0; i < 16; ++i){
    int gg = gg0 + i;
    float rv = (sc >= 0.f) ? rawmax[(size_t)gg*256 + t] : rawmin[(size_t)gg*256 + t];
    opool[(size_t)gg*256 + t] = fmaxf(fmaf(rv, sc, sh), 0.f);
  }
}

// ---------------- launch ----------------------------------------------------
extern "C" void kernel_launch(void* const* d_in, const int* in_sizes, int n_in,
                              void* d_out, int out_size, void* d_ws, size_t ws_size,
                              hipStream_t stream)
{
  const float* xyz    = (const float*)d_in[0];
  const float* points = (const float*)d_in[1];
  const float* W1  = (const float*)d_in[2];
  const float* b1  = (const float*)d_in[3];
  const float* g1  = (const float*)d_in[4];
  const float* be1 = (const float*)d_in[5];
  const float* W2  = (const float*)d_in[6];
  const float* b2  = (const float*)d_in[7];
  const float* g2  = (const float*)d_in[8];
  const float* be2 = (const float*)d_in[9];
  const float* W3  = (const float*)d_in[10];
  const float* b3  = (const float*)d_in[11];
  const float* g3  = (const float*)d_in[12];
  const float* be3 = (const float*)d_in[13];

  float* out    = (float*)d_out;
  float* center = out;                      // [B,G,3]
  float* opool  = out + (size_t)BB*GG*3;    // [B,G,256]

  char* ws = (char*)d_ws;
  size_t off = 0;
  auto alloc = [&](size_t bytes) -> void* {
    void* p = ws + off;
    off += (bytes + 255) & ~(size_t)255;
    return p;
  };
  unsigned short* Y1   = (unsigned short*)alloc((size_t)262144*128*2);
  unsigned short* Y2   = (unsigned short*)alloc((size_t)262144*128*2);
  int*   kidx = (int*)  alloc((size_t)262144*4);
  unsigned short* Wbf = (unsigned short*)alloc((size_t)65536*2);
  float* rawmax = (float*)alloc((size_t)8192*256*4);
  float* rawmin = (float*)alloc((size_t)8192*256*4);
  float* psumA = (float*)alloc((size_t)2*64*128*4);
  float* psumB = (float*)alloc((size_t)2*64*128*4);
  float* psumC = (float*)alloc((size_t)2*64*256*4);
  float* xsb  = (float*)alloc((size_t)131072*4);
  float* ysb  = (float*)alloc((size_t)131072*4);
  float* zsb  = (float*)alloc((size_t)131072*4);
  float* ppsb = (float*)alloc((size_t)131072*4);
  float* ddws = (float*)alloc((size_t)16*1024*8*4);
  unsigned short* pointsbf = Y2;            // aliases Y2; consumed before Y2 write

  hipMemsetAsync(psumA, 0, (size_t)(2*64*128 + 2*64*128 + 2*64*256)*4 + 1024, stream);

  fps_phase<0><<<BB + 2048, 1024, 0, stream>>>(
      xyz, points, W1, W2, W3, center, ddws, xsb, ysb, zsb, ppsb,
      Wbf, pointsbf, kidx, b1, Y1, psumA);
  fps_phase<1><<<BB + 256, 1024, 0, stream>>>(
      xyz, points, W1, W2, W3, center, ddws, xsb, ysb, zsb, ppsb,
      Wbf, pointsbf, kidx, b1, Y1, psumA);
  fps_phase<2><<<BB + 512, 1024, 0, stream>>>(
      xyz, points, W1, W2, W3, center, ddws, xsb, ysb, zsb, ppsb,
      Wbf, pointsbf, kidx, b1, Y1, psumA);
  fps_phase<3><<<BB + 512, 1024, 0, stream>>>(
      xyz, points, W1, W2, W3, center, ddws, xsb, ysb, zsb, ppsb,
      Wbf, pointsbf, kidx, b1, Y1, psumA);
  fps_phase<4><<<BB + 128 + 256, 1024, 0, stream>>>(
      xyz, points, W1, W2, W3, center, ddws, xsb, ysb, zsb, ppsb,
      Wbf, pointsbf, kidx, b1, Y1, psumA);

  knn_gemm_tail<<<1024, 256, 0, stream>>>(
      xsb, ysb, zsb, ppsb, center, kidx, Wbf, b1, pointsbf, Y1, psumA);
  gemm1e_kernel<<<512, 256, 0, stream>>>(Wbf, b1, pointsbf, kidx, Y1, psumA);

  // layer 2: two tiles per block, hoisted bnprep+A
  gemm23_kernel<128, true, false><<<2048, 256, 0, stream>>>(
      Wbf + 16384, b2, Y1, psumA, g1, be1, Y2, psumB, nullptr, nullptr);

  // layer 3: two tiles per block, hoisted bnprep+A
  gemm23_kernel<256, false, true><<<2048, 256, 0, stream>>>(
      Wbf + 32768, b3, Y2, psumB, g2, be2, nullptr, psumC, rawmax, rawmin);

  finish3_kernel<<<512, 256, 0, stream>>>(psumC, g3, be3, rawmax, rawmin, opool);
}